// Round 4
// baseline (804.166 us; speedup 1.0000x reference)
//
#include <hip/hip_runtime.h>

// ---------------------------------------------------------------------------
// EncoderLayer: pre-LN attn (gated by iter!=0) + causal-mult-mask attention +
// residual + pre-LN FFN(GELU) + residual.  B=8 S=1024 D=1024 FF=4096 H=16 Dh=64
// R4: gemm8 with JIT per-phase ds_reads (low register pressure), FIFO staging
// A0,B0,B1,A1 + counted vmcnt (never 0 in steady state), full (row&7)<<4 LDS
// swizzle (R3: 0 bank conflicts), bijective XCD blockIdx swizzle.
// ---------------------------------------------------------------------------

#define B_N 8
#define SEQ 1024
#define DM 1024
#define DFF 4096
#define NH 16
#define DH 64
#define MROWS (B_N * SEQ) // 8192

typedef __attribute__((ext_vector_type(4))) float f32x4;
typedef __attribute__((ext_vector_type(8))) short short8;
typedef __attribute__((ext_vector_type(4))) unsigned short us4;
typedef unsigned short u16;

__device__ __forceinline__ float b2f(u16 u) { return __uint_as_float(((unsigned)u) << 16); }
__device__ __forceinline__ u16 f2b(float f) {
    unsigned u = __float_as_uint(f);
    return (u16)((u + 0x7fffu + ((u >> 16) & 1u)) >> 16); // RNE
}
__device__ __forceinline__ float gelu_f(float x) {
    float t = tanhf(0.7978845608028654f * (x + 0.044715f * x * x * x));
    return 0.5f * x * (1.0f + t);
}
__device__ __forceinline__ void async_cp16(const void* g, void* l) {
    __builtin_amdgcn_global_load_lds(
        (const __attribute__((address_space(1))) unsigned int*)g,
        (__attribute__((address_space(3))) unsigned int*)l, 16, 0, 0);
}

// ---------------------------------------------------------------------------
// 8-phase GEMM: C[m][n] = (sum_k A[m][k]*Bt[n][k] + bias[n]) * scale
// 512 thr = 8 waves (2M x 4N), BK=64, double-buffered LDS, wave tile BM/2 x 64.
// Phases per K-tile: (m0,n0),(m0,n1),(m1,n0),(m1,n1).  A-half read once per
// 2 phases (8 ds_read_b128, 32 VGPR live); B pair re-read per phase (4 reads).
// Stage order A0,B0,B1,A1 == consumption FIFO; waits end-ph1 vmcnt(2LA),
// end-ph2 vmcnt(LA+LB), end-ph4 vmcnt(LA+LB).  Never 0 in steady loop.
// Swizzle: in-row byte ^= ((row&7)<<4) on stage-source and read (0 conflicts).
// EPI: 0 = bf16 out; 1 = bf16 GELU out; 2 = fp32 C += v
// ---------------------------------------------------------------------------
#define WAITV(N) asm volatile("s_waitcnt vmcnt(%0)" ::"i"(N) : "memory")

#define PH_SYNC()                                                               \
    __builtin_amdgcn_s_barrier();                                               \
    asm volatile("s_waitcnt lgkmcnt(0)" ::: "memory");                          \
    __builtin_amdgcn_s_setprio(1)

#define RD_A(dst, c, mh)                                                        \
    _Pragma("unroll") for (int m2 = 0; m2 < MFH; ++m2)                          \
    _Pragma("unroll") for (int ks = 0; ks < 2; ++ks)                            \
        dst[m2][ks] = *(const short8*)(Abase + (c) * BUFB + (mh) * AH + m2 * 2048 + ksx[ks])

#define RD_B(dst, c, nh)                                                        \
    _Pragma("unroll") for (int f = 0; f < 2; ++f)                               \
    _Pragma("unroll") for (int ks = 0; ks < 2; ++ks)                            \
        dst[f][ks] = *(const short8*)(Bbase + (c) * BUFB + (nh) * BH + f * 2048 + ksx[ks])

#define G8_MFMA(Af, Bf, MO, NO)                                                 \
    _Pragma("unroll") for (int ks = 0; ks < 2; ++ks)                            \
    _Pragma("unroll") for (int m2 = 0; m2 < MFH; ++m2)                          \
    _Pragma("unroll") for (int f = 0; f < 2; ++f)                               \
        acc[(MO) + m2][(NO) + f] = __builtin_amdgcn_mfma_f32_16x16x32_bf16(     \
            Af[m2][ks], Bf[f][ks], acc[(MO) + m2][(NO) + f], 0, 0, 0)

#define G8_TILE(c, t, ST)                                                       \
    {                                                                           \
        short8 Af[MFH][2], Bf[2][2];                                            \
        /* ph1 (m0,n0): stage next A0 */                                        \
        RD_A(Af, c, 0); RD_B(Bf, c, 0);                                         \
        if (ST) stageA(1 - (c), 0, (t) + 1);                                    \
        PH_SYNC(); G8_MFMA(Af, Bf, 0, 0);                                       \
        __builtin_amdgcn_s_setprio(0);                                          \
        if (ST) { WAITV(2 * LA); } else { WAITV(LA); }                          \
        __builtin_amdgcn_s_barrier();                                           \
        /* ph2 (m0,n1): stage next B0 */                                        \
        RD_B(Bf, c, 1);                                                         \
        if (ST) stageB(1 - (c), 0, (t) + 1);                                    \
        PH_SYNC(); G8_MFMA(Af, Bf, 0, 2);                                       \
        __builtin_amdgcn_s_setprio(0);                                          \
        if (ST) { WAITV(LA + LB); } else { WAITV(0); }                          \
        __builtin_amdgcn_s_barrier();                                           \
        /* ph3 (m1,n0): stage next B1 */                                        \
        RD_A(Af, c, 1); RD_B(Bf, c, 0);                                         \
        if (ST) stageB(1 - (c), 1, (t) + 1);                                    \
        PH_SYNC(); G8_MFMA(Af, Bf, MFH, 0);                                     \
        __builtin_amdgcn_s_setprio(0);                                          \
        __builtin_amdgcn_s_barrier();                                           \
        /* ph4 (m1,n1): stage next A1 */                                        \
        RD_B(Bf, c, 1);                                                         \
        if (ST) stageA(1 - (c), 1, (t) + 1);                                    \
        PH_SYNC(); G8_MFMA(Af, Bf, MFH, 2);                                     \
        __builtin_amdgcn_s_setprio(0);                                          \
        if (ST) { WAITV(LA + LB); }                                             \
        __builtin_amdgcn_s_barrier();                                           \
    }

template <int BM, int BN, int EPI>
__global__ __launch_bounds__(512, 2) void gemm8(
    const u16* __restrict__ A, int lda,
    const u16* __restrict__ Bt, int ldb,
    void* __restrict__ C, int ldc,
    const float* __restrict__ bias, float scale, int K)
{
    constexpr int MF = BM / 32;       // m-frags per wave
    constexpr int MFH = MF / 2;       // m-frags per quadrant
    constexpr int WMROWS = BM / 2;    // rows per wm group
    constexpr int MH = BM / 4;        // rows per m-half per wm group
    constexpr int AH = BM * 64;       // bytes per A-half ((BM/2) rows x 128B)
    constexpr int BH = 16384;         // bytes per B-half (128 rows x 128B)
    constexpr int LA = BM / 128;      // stage insts/thread per A-half
    constexpr int LB = 2;
    constexpr int BUFB = 2 * AH + 2 * BH;
    __shared__ __align__(16) char lds[2 * BUFB];

    const int tid = threadIdx.x;
    const int lane = tid & 63;
    const int w = tid >> 6;
    const int wm = w >> 2, wn = w & 3;
    const int rr = lane & 15, qq = lane >> 4;

    // bijective XCD swizzle (nwg % 8 == 0 for all launches here)
    const int nwg = gridDim.x * gridDim.y;
    int flat = blockIdx.y * gridDim.x + blockIdx.x;
    flat = (flat & 7) * (nwg >> 3) + (flat >> 3);
    const int m0 = (flat / gridDim.x) * BM;
    const int n0 = (flat % gridDim.x) * BN;

    // read-side swizzle: in-row byte ^= ((row&7)<<4); row&7 == rr&7 always
    const int s = (rr & 7) << 4;
    const int swq = (qq * 16) ^ (s & 48);
    const int ksx[2] = { 0 ^ (s & 64), 64 ^ (s & 64) };
    const char* Abase = lds + (size_t)(wm * MH + rr) * 128 + swq;
    const char* Bbase = lds + 2 * AH + (size_t)(wn * 32 + rr) * 128 + swq;

    f32x4 acc[MF][4];
#pragma unroll
    for (int i = 0; i < MF; i++)
#pragma unroll
        for (int j = 0; j < 4; j++)
#pragma unroll
            for (int e = 0; e < 4; e++) acc[i][j][e] = 0.f;

    // stage: linear LDS dest granule g; source granule swizzle-permuted
    // (involution: low3 ^= row&7) so swizzled reads see logical data.
    auto stageA = [&](int nb, int h, int t) {
#pragma unroll
        for (int i = 0; i < LA; ++i) {
            int g = tid + i * 512;
            int gs = (g & ~7) | ((g ^ (g >> 3)) & 7);
            int lr = gs >> 3;
            int grow = m0 + ((lr >= MH) ? WMROWS : 0) + h * MH + (lr & (MH - 1));
            const u16* src = A + (size_t)grow * lda + (t << 6) + ((gs & 7) << 3);
            async_cp16(src, lds + nb * BUFB + h * AH + g * 16);
        }
    };
    auto stageB = [&](int nb, int h, int t) {
#pragma unroll
        for (int i = 0; i < LB; ++i) {
            int g = tid + i * 512;
            int gs = (g & ~7) | ((g ^ (g >> 3)) & 7);
            int lr = gs >> 3;
            int gcol = n0 + ((lr >> 5) << 6) + h * 32 + (lr & 31);
            const u16* src = Bt + (size_t)gcol * ldb + (t << 6) + ((gs & 7) << 3);
            async_cp16(src, lds + nb * BUFB + 2 * AH + h * BH + g * 16);
        }
    };

    // prologue: stage tile 0 in consumption order; counted wait (B1,A1 fly)
    stageA(0, 0, 0); stageB(0, 0, 0); stageB(0, 1, 0); stageA(0, 1, 0);
    WAITV(LA + LB);
    __builtin_amdgcn_s_barrier();

    const int NT = K >> 6; // K-tiles of 64 (16 or 64 here; always even)
    int t = 0;
    for (; t < NT - 2; t += 2) {
        G8_TILE(0, t, true);
        G8_TILE(1, t + 1, true);
    }
    G8_TILE(0, t, true);
    G8_TILE(1, t + 1, false);

    // epilogue: C/D layout col=lane&15, row=(lane>>4)*4+j
    const int ccol = n0 + wn * 64 + rr;
    const int crow = m0 + wm * WMROWS + qq * 4;
#pragma unroll
    for (int mi = 0; mi < MF; ++mi) {
#pragma unroll
        for (int ni = 0; ni < 4; ++ni) {
            const int colg = ccol + ni * 16;
            const float bv = bias ? bias[colg] : 0.f;
#pragma unroll
            for (int j = 0; j < 4; ++j) {
                const int rowg = crow + mi * 16 + j;
                float v = (acc[mi][ni][j] + bv) * scale;
                size_t idx = (size_t)rowg * ldc + colg;
                if (EPI == 1) v = gelu_f(v);
                if (EPI == 2) ((float*)C)[idx] += v;
                else ((u16*)C)[idx] = f2b(v);
            }
        }
    }
}

// ---------------------------------------------------------------------------
// R1 128^2 GEMM kept for the attention QK^T / PV steps (small K / batched z).
// ---------------------------------------------------------------------------
template <int TM, int TN, int WC, int EPI>
__global__ __launch_bounds__(256) void gemm_bf16(
    const u16* __restrict__ A, long long sA1, long long sA2, int lda,
    const u16* __restrict__ Bt, long long sB1, long long sB2, int ldb,
    void* __restrict__ C, long long sC1, long long sC2, int ldc,
    const float* __restrict__ bias, float scale, int K)
{
    __shared__ __align__(16) u16 smem[(TM + TN) * 32];
    u16* As = smem;
    u16* Bs = smem + TM * 32;

    const int tid = threadIdx.x;
    const int lane = tid & 63;
    const int w = tid >> 6;
    const int wr = w / WC, wc = w % WC;

    const int z = blockIdx.z;
    const int zq = z >> 4, zr = z & 15;
    const u16* Ab = A + (long long)zq * sA1 + (long long)zr * sA2;
    const u16* Bb = Bt + (long long)zq * sB1 + (long long)zr * sB2;

    const int m0 = blockIdx.y * TM;
    const int n0 = blockIdx.x * TN;

    f32x4 acc[4][4];
#pragma unroll
    for (int i = 0; i < 4; i++)
#pragma unroll
        for (int j = 0; j < 4; j++)
#pragma unroll
            for (int e = 0; e < 4; e++) acc[i][j][e] = 0.f;

    for (int kt = 0; kt < K; kt += 32) {
#pragma unroll
        for (int i = 0; i < TM / 64; i++) {
            int g = tid + i * 256;
            int row = g >> 2;
            int cole = (g & 3) << 3;
            async_cp16(Ab + (size_t)(m0 + row) * lda + kt + cole, (char*)As + g * 16);
        }
#pragma unroll
        for (int i = 0; i < TN / 64; i++) {
            int g = tid + i * 256;
            int row = g >> 2;
            int cole = (g & 3) << 3;
            async_cp16(Bb + (size_t)(n0 + row) * ldb + kt + cole, (char*)Bs + g * 16);
        }
        __syncthreads();

        short8 af[4], bfr[4];
        const int rr = lane & 15;
        const int kb = (lane >> 4) << 3;
#pragma unroll
        for (int mi = 0; mi < 4; mi++)
            af[mi] = *(const short8*)&As[(wr * 64 + mi * 16 + rr) * 32 + kb];
#pragma unroll
        for (int ni = 0; ni < 4; ni++)
            bfr[ni] = *(const short8*)&Bs[(wc * 64 + ni * 16 + rr) * 32 + kb];
#pragma unroll
        for (int mi = 0; mi < 4; mi++)
#pragma unroll
            for (int ni = 0; ni < 4; ni++)
                acc[mi][ni] = __builtin_amdgcn_mfma_f32_16x16x32_bf16(
                    af[mi], bfr[ni], acc[mi][ni], 0, 0, 0);
        __syncthreads();
    }

    const long long cz = (long long)zq * sC1 + (long long)zr * sC2;
    const int r0 = (lane >> 4) << 2;
    const int ccol = lane & 15;
#pragma unroll
    for (int mi = 0; mi < 4; mi++) {
#pragma unroll
        for (int ni = 0; ni < 4; ni++) {
            int colg = n0 + wc * 64 + ni * 16 + ccol;
            float bv = bias ? bias[colg] : 0.f;
#pragma unroll
            for (int j = 0; j < 4; j++) {
                int rowg = m0 + wr * 64 + mi * 16 + r0 + j;
                float v = (acc[mi][ni][j] + bv) * scale;
                long long idx = cz + (long long)rowg * ldc + colg;
                if (EPI == 1) v = gelu_f(v);
                if (EPI == 2) {
                    float* Cf = (float*)C;
                    Cf[idx] += v;
                } else {
                    ((u16*)C)[idx] = f2b(v);
                }
            }
        }
    }
}

// ---------------------------------------------------------------------------
__global__ __launch_bounds__(256) void ln_bf16(
    const float* __restrict__ in, const float* __restrict__ gg,
    const float* __restrict__ bb, u16* __restrict__ outp,
    const int* __restrict__ iterp)
{
    const int row = blockIdx.x;
    const int t = threadIdx.x;
    const int lane = t & 63, w = t >> 6;
    const float* r = in + (size_t)row * DM;
    f32x4 x = *(const f32x4*)(r + t * 4);
    __shared__ float red[4];

    float s = x[0] + x[1] + x[2] + x[3];
#pragma unroll
    for (int o = 32; o; o >>= 1) s += __shfl_xor(s, o, 64);
    if (lane == 0) red[w] = s;
    __syncthreads();
    float mu = (red[0] + red[1] + red[2] + red[3]) * (1.0f / DM);
    __syncthreads();

    float d0 = x[0] - mu, d1 = x[1] - mu, d2 = x[2] - mu, d3 = x[3] - mu;
    float q = d0 * d0 + d1 * d1 + d2 * d2 + d3 * d3;
#pragma unroll
    for (int o = 32; o; o >>= 1) q += __shfl_xor(q, o, 64);
    if (lane == 0) red[w] = q;
    __syncthreads();
    float rs = rsqrtf((red[0] + red[1] + red[2] + red[3]) * (1.0f / DM) + 1e-6f);

    bool apply = !(iterp && iterp[0] == 0);
    f32x4 gv = *(const f32x4*)(gg + t * 4);
    f32x4 bv = *(const f32x4*)(bb + t * 4);
    us4 o;
    if (apply) {
        o[0] = f2b(d0 * rs * gv[0] + bv[0]);
        o[1] = f2b(d1 * rs * gv[1] + bv[1]);
        o[2] = f2b(d2 * rs * gv[2] + bv[2]);
        o[3] = f2b(d3 * rs * gv[3] + bv[3]);
    } else {
        o[0] = f2b(x[0]); o[1] = f2b(x[1]); o[2] = f2b(x[2]); o[3] = f2b(x[3]);
    }
    *(us4*)(outp + (size_t)row * DM + t * 4) = o;
}

// ---------------------------------------------------------------------------
__global__ __launch_bounds__(256) void softmax_mask(u16* __restrict__ sc)
{
    const int qrow = blockIdx.x;
    u16* rowp = sc + ((size_t)blockIdx.y << 20) + (size_t)qrow * SEQ;
    const int t = threadIdx.x, lane = t & 63, w = t >> 6;
    __shared__ float red[4];

    us4 r4 = *(const us4*)(rowp + t * 4);
    float v[4];
#pragma unroll
    for (int j = 0; j < 4; j++) {
        int k = t * 4 + j;
        v[j] = (k <= qrow) ? b2f(r4[j]) : 0.f;
    }
    float m = fmaxf(fmaxf(v[0], v[1]), fmaxf(v[2], v[3]));
#pragma unroll
    for (int o = 32; o; o >>= 1) m = fmaxf(m, __shfl_xor(m, o, 64));
    if (lane == 0) red[w] = m;
    __syncthreads();
    m = fmaxf(fmaxf(red[0], red[1]), fmaxf(red[2], red[3]));
    __syncthreads();
    float e0 = expf(v[0] - m), e1 = expf(v[1] - m), e2 = expf(v[2] - m), e3 = expf(v[3] - m);
    float s = e0 + e1 + e2 + e3;
#pragma unroll
    for (int o = 32; o; o >>= 1) s += __shfl_xor(s, o, 64);
    if (lane == 0) red[w] = s;
    __syncthreads();
    float inv = 1.0f / (red[0] + red[1] + red[2] + red[3]);
    us4 o;
    o[0] = f2b(e0 * inv); o[1] = f2b(e1 * inv); o[2] = f2b(e2 * inv); o[3] = f2b(e3 * inv);
    *(us4*)(rowp + t * 4) = o;
}

__global__ void transW(const float* __restrict__ W, u16* __restrict__ WT, int Kd, int Nd)
{
    __shared__ float tile[32][33];
    int bx = blockIdx.x << 5, by = blockIdx.y << 5;
    int tx = threadIdx.x, ty = threadIdx.y;
#pragma unroll
    for (int i = 0; i < 32; i += 8)
        tile[ty + i][tx] = W[(size_t)(by + ty + i) * Nd + bx + tx];
    __syncthreads();
#pragma unroll
    for (int i = 0; i < 32; i += 8)
        WT[(size_t)(bx + ty + i) * Kd + by + tx] = f2b(tile[tx][ty + i]);
}

__global__ void transV(const u16* __restrict__ Vb, u16* __restrict__ Vt)
{
    __shared__ u16 tile[32][33];
    int s0 = blockIdx.x << 5, d0 = blockIdx.y << 5, bh = blockIdx.z;
    int b = bh >> 4, h = bh & 15;
    int tx = threadIdx.x, ty = threadIdx.y;
#pragma unroll
    for (int i = 0; i < 32; i += 8)
        tile[ty + i][tx] = Vb[(size_t)((b << 10) + s0 + ty + i) * DM + (h << 6) + d0 + tx];
    __syncthreads();
#pragma unroll
    for (int i = 0; i < 32; i += 8)
        Vt[((size_t)bh << 16) + (size_t)(d0 + ty + i) * SEQ + s0 + tx] = tile[tx][ty + i];
}

__global__ __launch_bounds__(256) void resid_add(
    const u16* __restrict__ ctx, const float* __restrict__ x, float* __restrict__ outp)
{
    size_t i = ((size_t)blockIdx.x * 256 + threadIdx.x) * 4;
    us4 c = *(const us4*)(ctx + i);
    f32x4 xv = *(const f32x4*)(x + i);
    f32x4 o;
#pragma unroll
    for (int j = 0; j < 4; j++) o[j] = xv[j] + b2f(c[j]);
    *(f32x4*)(outp + i) = o;
}

// ---------------------------------------------------------------------------
extern "C" void kernel_launch(void* const* d_in, const int* in_sizes, int n_in,
                              void* d_out, int out_size, void* d_ws, size_t ws_size,
                              hipStream_t stream)
{
    const int* iter = (const int*)d_in[0];
    const float* x = (const float*)d_in[1];
    const float* Wq = (const float*)d_in[3];
    const float* bq = (const float*)d_in[4];
    const float* Wk = (const float*)d_in[5];
    const float* bk = (const float*)d_in[6];
    const float* Wv = (const float*)d_in[7];
    const float* bv = (const float*)d_in[8];
    const float* W1 = (const float*)d_in[9];
    const float* b1 = (const float*)d_in[10];
    const float* W2 = (const float*)d_in[11];
    const float* b2 = (const float*)d_in[12];
    const float* lag = (const float*)d_in[13];
    const float* lab = (const float*)d_in[14];
    const float* lfg = (const float*)d_in[15];
    const float* lfb = (const float*)d_in[16];
    float* out = (float*)d_out;

    char* ws = (char*)d_ws;
    size_t off = 0;
    auto alloc = [&](size_t bytes) {
        char* p = ws + off;
        off += (bytes + 255) & ~(size_t)255;
        return p;
    };
    u16* NXb = (u16*)alloc((size_t)MROWS * DM * 2);
    u16* Qb  = (u16*)alloc((size_t)MROWS * DM * 2);
    u16* Kb  = (u16*)alloc((size_t)MROWS * DM * 2);
    u16* Vb  = (u16*)alloc((size_t)MROWS * DM * 2);
    u16* ctx = (u16*)alloc((size_t)MROWS * DM * 2);
    u16* h2  = (u16*)alloc((size_t)MROWS * DFF * 2);
    u16* WqT = (u16*)alloc((size_t)DM * DM * 2);
    u16* WkT = (u16*)alloc((size_t)DM * DM * 2);
    u16* WvT = (u16*)alloc((size_t)DM * DM * 2);
    u16* W1T = (u16*)alloc((size_t)DM * DFF * 2);
    u16* W2T = (u16*)alloc((size_t)DM * DFF * 2);
    u16* Vt = NXb;
    u16* h1 = Qb;
    u16* scores = h2;

    dim3 tb(32, 8);
    transW<<<dim3(DM / 32, DM / 32), tb, 0, stream>>>(Wq, WqT, DM, DM);
    transW<<<dim3(DM / 32, DM / 32), tb, 0, stream>>>(Wk, WkT, DM, DM);
    transW<<<dim3(DM / 32, DM / 32), tb, 0, stream>>>(Wv, WvT, DM, DM);
    transW<<<dim3(DFF / 32, DM / 32), tb, 0, stream>>>(W1, W1T, DM, DFF);
    transW<<<dim3(DM / 32, DFF / 32), tb, 0, stream>>>(W2, W2T, DFF, DM);

    ln_bf16<<<MROWS, 256, 0, stream>>>(x, lag, lab, NXb, iter);

    // projections (8-phase 128x256): Q scaled by 1/sqrt(64)
    gemm8<128, 256, 0><<<dim3(DM / 256, MROWS / 128), 512, 0, stream>>>(
        NXb, DM, WqT, DM, Qb, DM, bq, 0.125f, DM);
    gemm8<128, 256, 0><<<dim3(DM / 256, MROWS / 128), 512, 0, stream>>>(
        NXb, DM, WkT, DM, Kb, DM, bk, 1.0f, DM);
    gemm8<128, 256, 0><<<dim3(DM / 256, MROWS / 128), 512, 0, stream>>>(
        NXb, DM, WvT, DM, Vb, DM, bv, 1.0f, DM);

    transV<<<dim3(SEQ / 32, DH / 32, B_N * NH), tb, 0, stream>>>(Vb, Vt);

    // attention in 4 chunks of 32 heads (R1 kernels)
    for (int c = 0; c < 4; ++c) {
        const u16* Qc = Qb + (size_t)c * 2 * 1048576;
        const u16* Kc = Kb + (size_t)c * 2 * 1048576;
        gemm_bf16<128, 128, 2, 0><<<dim3(8, 8, 32), 256, 0, stream>>>(
            Qc, 1048576, 64, DM, Kc, 1048576, 64, DM,
            scores, 16777216, 1048576, SEQ, nullptr, 1.0f, DH);
        softmax_mask<<<dim3(SEQ, 32), 256, 0, stream>>>(scores);
        gemm_bf16<256, 64, 1, 0><<<dim3(1, 4, 32), 256, 0, stream>>>(
            scores, 16777216, 1048576, SEQ,
            Vt + (size_t)c * 2097152, 1048576, 65536, SEQ,
            (void*)(ctx + (size_t)c * 2097152), 1048576, 65536, DH,
            nullptr, 1.0f, SEQ);
    }

    resid_add<<<(MROWS * DM) / 1024, 256, 0, stream>>>(ctx, x, out);

    // FFN: h1 = LN(out); h2 = gelu(h1@W1+b1) [256^2]; out += h2@W2+b2 [128x256]
    ln_bf16<<<MROWS, 256, 0, stream>>>(out, lfg, lfb, h1, nullptr);
    gemm8<256, 256, 1><<<dim3(DFF / 256, MROWS / 256), 512, 0, stream>>>(
        h1, DM, W1T, DM, h2, DFF, b1, 1.0f, DM);
    gemm8<128, 256, 2><<<dim3(DM / 256, MROWS / 128), 512, 0, stream>>>(
        h2, DFF, W2T, DFF, (void*)out, DM, b2, 1.0f, DFF);
}

// Round 5
// 754.536 us; speedup vs baseline: 1.0658x; 1.0658x over previous
//
#include <hip/hip_runtime.h>

// ---------------------------------------------------------------------------
// EncoderLayer: pre-LN attn (gated by iter!=0) + causal-mult-mask attention +
// residual + pre-LN FFN(GELU) + residual.  B=8 S=1024 D=1024 FF=4096 H=16 Dh=64
// R5: big GEMMs on the VERIFIED minimum 2-phase recipe (T3 box): per K-tile
// { stage next tile -> ds_read current -> lgkmcnt(0) -> MFMA -> vmcnt(0) ->
//   barrier }, double-buffered LDS, A-half split to keep frag VGPRs <= 64
// (R3 spill lesson), proven 0-conflict (row&7)<<4 swizzle, XCD swizzle.
// ---------------------------------------------------------------------------

#define B_N 8
#define SEQ 1024
#define DM 1024
#define DFF 4096
#define NH 16
#define DH 64
#define MROWS (B_N * SEQ) // 8192

typedef __attribute__((ext_vector_type(4))) float f32x4;
typedef __attribute__((ext_vector_type(8))) short short8;
typedef __attribute__((ext_vector_type(4))) unsigned short us4;
typedef unsigned short u16;

__device__ __forceinline__ float b2f(u16 u) { return __uint_as_float(((unsigned)u) << 16); }
__device__ __forceinline__ u16 f2b(float f) {
    unsigned u = __float_as_uint(f);
    return (u16)((u + 0x7fffu + ((u >> 16) & 1u)) >> 16); // RNE
}
__device__ __forceinline__ float gelu_f(float x) {
    float t = tanhf(0.7978845608028654f * (x + 0.044715f * x * x * x));
    return 0.5f * x * (1.0f + t);
}
__device__ __forceinline__ void async_cp16(const void* g, void* l) {
    __builtin_amdgcn_global_load_lds(
        (const __attribute__((address_space(1))) unsigned int*)g,
        (__attribute__((address_space(3))) unsigned int*)l, 16, 0, 0);
}

#define WAITV0() asm volatile("s_waitcnt vmcnt(0)" ::: "memory")
#define WAITL0()                                                                \
    asm volatile("s_waitcnt lgkmcnt(0)" ::: "memory");                          \
    __builtin_amdgcn_sched_barrier(0)

// ---------------------------------------------------------------------------
// 2-phase GEMM: C[m][n] = (sum_k A[m][k]*Bt[n][k] + bias[n]) * scale
// 512 thr = 8 waves (2M x 4N), BN=256, BK=64, double-buffered LDS.
// Per K-tile: stage(next) ; read B(8 b128)+A-half0(MFH*2) ; lgkm0 ; MFMA ;
//             read A-half1 (reuse regs) ; lgkm0 ; MFMA ; vmcnt0 ; barrier.
// Swizzle: in-row byte ^= ((row&7)<<4) on stage-source granule and read
// address (R3/R4-verified: 0 bank conflicts).
// EPI: 0 = bf16 out; 1 = bf16 GELU out; 2 = fp32 C += v
// ---------------------------------------------------------------------------
template <int BM, int EPI>
__global__ __launch_bounds__(512, 2) void gemm2(
    const u16* __restrict__ A, int lda,
    const u16* __restrict__ Bt, int ldb,
    void* __restrict__ C, int ldc,
    const float* __restrict__ bias, float scale, int K)
{
    constexpr int BN = 256;
    constexpr int MF = BM / 32;      // m-frags per wave (wave rows = BM/2)
    constexpr int MFH = MF / 2;
    constexpr int ABYT = BM * 128;   // A tile bytes ([BM][64] bf16)
    constexpr int BBYT = BN * 128;   // B tile bytes ([256][64] bf16)
    constexpr int LA = ABYT / 8192;  // gload insts/thread (512 thr x 16B)
    constexpr int LB = BBYT / 8192;  // 4
    constexpr int BUFB = ABYT + BBYT;
    __shared__ __align__(16) char lds[2 * BUFB];

    const int tid = threadIdx.x;
    const int lane = tid & 63;
    const int w = tid >> 6;
    const int wm = w >> 2, wn = w & 3;
    const int rr = lane & 15, qq = lane >> 4;

    // bijective XCD swizzle (all grids here have nwg % 8 == 0)
    const int nwg = gridDim.x * gridDim.y;
    int flat = blockIdx.y * gridDim.x + blockIdx.x;
    flat = (flat & 7) * (nwg >> 3) + (flat >> 3);
    const int m0 = (flat / gridDim.x) * BM;
    const int n0 = (flat % gridDim.x) * BN;

    // read-side swizzle: row&7 == rr&7 for all fragment rows
    const int s = (rr & 7) << 4;
    const int swq = (qq * 16) ^ (s & 48);
    const int ksx[2] = { s & 64, 64 ^ (s & 64) };
    const int aoff = (wm * (BM / 2) + rr) * 128 + swq;         // within buffer
    const int boff = ABYT + (wn * 64 + rr) * 128 + swq;

    f32x4 acc[MF][4];
#pragma unroll
    for (int i = 0; i < MF; i++)
#pragma unroll
        for (int j = 0; j < 4; j++)
#pragma unroll
            for (int e = 0; e < 4; e++) acc[i][j][e] = 0.f;

    // stage full tile t into buffer nb: linear LDS dest, source granule
    // low3 ^= (row&7) (involution matching the read swizzle)
    auto stage = [&](int nb, int t) {
        char* dst = lds + nb * BUFB;
#pragma unroll
        for (int i = 0; i < LA; ++i) {
            int g = tid + i * 512;
            int gs = (g & ~7) | ((g ^ (g >> 3)) & 7);
            async_cp16(A + (size_t)(m0 + (gs >> 3)) * lda + (t << 6) + ((gs & 7) << 3),
                       dst + g * 16);
        }
#pragma unroll
        for (int i = 0; i < LB; ++i) {
            int g = tid + i * 512;
            int gs = (g & ~7) | ((g ^ (g >> 3)) & 7);
            async_cp16(Bt + (size_t)(n0 + (gs >> 3)) * ldb + (t << 6) + ((gs & 7) << 3),
                       dst + ABYT + g * 16);
        }
    };

    // one K-tile of compute from buffer `buf` (B all frags + A in 2 halves)
    auto ktile = [&](const char* buf) {
        short8 bfr[4][2], afr[MFH][2];
#pragma unroll
        for (int f = 0; f < 4; ++f)
#pragma unroll
            for (int ks = 0; ks < 2; ++ks)
                bfr[f][ks] = *(const short8*)(buf + boff + f * 2048 + ksx[ks]);
#pragma unroll
        for (int m2 = 0; m2 < MFH; ++m2)
#pragma unroll
            for (int ks = 0; ks < 2; ++ks)
                afr[m2][ks] = *(const short8*)(buf + aoff + m2 * 2048 + ksx[ks]);
        WAITL0();
        __builtin_amdgcn_s_setprio(1);
#pragma unroll
        for (int ks = 0; ks < 2; ++ks)
#pragma unroll
            for (int m2 = 0; m2 < MFH; ++m2)
#pragma unroll
                for (int f = 0; f < 4; ++f)
                    acc[m2][f] = __builtin_amdgcn_mfma_f32_16x16x32_bf16(
                        afr[m2][ks], bfr[f][ks], acc[m2][f], 0, 0, 0);
#pragma unroll
        for (int m2 = 0; m2 < MFH; ++m2)
#pragma unroll
            for (int ks = 0; ks < 2; ++ks)
                afr[m2][ks] = *(const short8*)(buf + aoff + (MFH + m2) * 2048 + ksx[ks]);
        WAITL0();
#pragma unroll
        for (int ks = 0; ks < 2; ++ks)
#pragma unroll
            for (int m2 = 0; m2 < MFH; ++m2)
#pragma unroll
                for (int f = 0; f < 4; ++f)
                    acc[MFH + m2][f] = __builtin_amdgcn_mfma_f32_16x16x32_bf16(
                        afr[m2][ks], bfr[f][ks], acc[MFH + m2][f], 0, 0, 0);
        __builtin_amdgcn_s_setprio(0);
    };

    // prologue
    stage(0, 0);
    WAITV0();
    __builtin_amdgcn_s_barrier();

    const int NT = K >> 6;
    for (int t = 0; t < NT - 1; ++t) {
        const int cur = t & 1;
        stage(1 - cur, t + 1);          // issue next-tile loads FIRST
        ktile(lds + cur * BUFB);        // compute current
        WAITV0();                       // next tile landed
        __builtin_amdgcn_s_barrier();
    }
    ktile(lds + ((NT - 1) & 1) * BUFB); // last tile, no prefetch

    // epilogue: C/D layout col=lane&15, row=(lane>>4)*4+j
    const int ccol = n0 + wn * 64 + rr;
    const int crow = m0 + wm * (BM / 2) + qq * 4;
#pragma unroll
    for (int mi = 0; mi < MF; ++mi) {
#pragma unroll
        for (int ni = 0; ni < 4; ++ni) {
            const int colg = ccol + ni * 16;
            const float bv = bias ? bias[colg] : 0.f;
#pragma unroll
            for (int j = 0; j < 4; ++j) {
                const int rowg = crow + mi * 16 + j;
                float v = (acc[mi][ni][j] + bv) * scale;
                size_t idx = (size_t)rowg * ldc + colg;
                if (EPI == 1) v = gelu_f(v);
                if (EPI == 2) ((float*)C)[idx] += v;
                else ((u16*)C)[idx] = f2b(v);
            }
        }
    }
}

// ---------------------------------------------------------------------------
// R1 128^2 GEMM kept for the attention QK^T / PV steps (small K / batched z).
// ---------------------------------------------------------------------------
template <int TM, int TN, int WC, int EPI>
__global__ __launch_bounds__(256) void gemm_bf16(
    const u16* __restrict__ A, long long sA1, long long sA2, int lda,
    const u16* __restrict__ Bt, long long sB1, long long sB2, int ldb,
    void* __restrict__ C, long long sC1, long long sC2, int ldc,
    const float* __restrict__ bias, float scale, int K)
{
    __shared__ __align__(16) u16 smem[(TM + TN) * 32];
    u16* As = smem;
    u16* Bs = smem + TM * 32;

    const int tid = threadIdx.x;
    const int lane = tid & 63;
    const int w = tid >> 6;
    const int wr = w / WC, wc = w % WC;

    const int z = blockIdx.z;
    const int zq = z >> 4, zr = z & 15;
    const u16* Ab = A + (long long)zq * sA1 + (long long)zr * sA2;
    const u16* Bb = Bt + (long long)zq * sB1 + (long long)zr * sB2;

    const int m0 = blockIdx.y * TM;
    const int n0 = blockIdx.x * TN;

    f32x4 acc[4][4];
#pragma unroll
    for (int i = 0; i < 4; i++)
#pragma unroll
        for (int j = 0; j < 4; j++)
#pragma unroll
            for (int e = 0; e < 4; e++) acc[i][j][e] = 0.f;

    for (int kt = 0; kt < K; kt += 32) {
#pragma unroll
        for (int i = 0; i < TM / 64; i++) {
            int g = tid + i * 256;
            int row = g >> 2;
            int cole = (g & 3) << 3;
            async_cp16(Ab + (size_t)(m0 + row) * lda + kt + cole, (char*)As + g * 16);
        }
#pragma unroll
        for (int i = 0; i < TN / 64; i++) {
            int g = tid + i * 256;
            int row = g >> 2;
            int cole = (g & 3) << 3;
            async_cp16(Bb + (size_t)(n0 + row) * ldb + kt + cole, (char*)Bs + g * 16);
        }
        __syncthreads();

        short8 af[4], bfr[4];
        const int rr = lane & 15;
        const int kb = (lane >> 4) << 3;
#pragma unroll
        for (int mi = 0; mi < 4; mi++)
            af[mi] = *(const short8*)&As[(wr * 64 + mi * 16 + rr) * 32 + kb];
#pragma unroll
        for (int ni = 0; ni < 4; ni++)
            bfr[ni] = *(const short8*)&Bs[(wc * 64 + ni * 16 + rr) * 32 + kb];
#pragma unroll
        for (int mi = 0; mi < 4; mi++)
#pragma unroll
            for (int ni = 0; ni < 4; ni++)
                acc[mi][ni] = __builtin_amdgcn_mfma_f32_16x16x32_bf16(
                    af[mi], bfr[ni], acc[mi][ni], 0, 0, 0);
        __syncthreads();
    }

    const long long cz = (long long)zq * sC1 + (long long)zr * sC2;
    const int r0 = (lane >> 4) << 2;
    const int ccol = lane & 15;
#pragma unroll
    for (int mi = 0; mi < 4; mi++) {
#pragma unroll
        for (int ni = 0; ni < 4; ni++) {
            int colg = n0 + wc * 64 + ni * 16 + ccol;
            float bv = bias ? bias[colg] : 0.f;
#pragma unroll
            for (int j = 0; j < 4; j++) {
                int rowg = m0 + wr * 64 + mi * 16 + r0 + j;
                float v = (acc[mi][ni][j] + bv) * scale;
                long long idx = cz + (long long)rowg * ldc + colg;
                if (EPI == 1) v = gelu_f(v);
                if (EPI == 2) {
                    float* Cf = (float*)C;
                    Cf[idx] += v;
                } else {
                    ((u16*)C)[idx] = f2b(v);
                }
            }
        }
    }
}

// ---------------------------------------------------------------------------
__global__ __launch_bounds__(256) void ln_bf16(
    const float* __restrict__ in, const float* __restrict__ gg,
    const float* __restrict__ bb, u16* __restrict__ outp,
    const int* __restrict__ iterp)
{
    const int row = blockIdx.x;
    const int t = threadIdx.x;
    const int lane = t & 63, w = t >> 6;
    const float* r = in + (size_t)row * DM;
    f32x4 x = *(const f32x4*)(r + t * 4);
    __shared__ float red[4];

    float s = x[0] + x[1] + x[2] + x[3];
#pragma unroll
    for (int o = 32; o; o >>= 1) s += __shfl_xor(s, o, 64);
    if (lane == 0) red[w] = s;
    __syncthreads();
    float mu = (red[0] + red[1] + red[2] + red[3]) * (1.0f / DM);
    __syncthreads();

    float d0 = x[0] - mu, d1 = x[1] - mu, d2 = x[2] - mu, d3 = x[3] - mu;
    float q = d0 * d0 + d1 * d1 + d2 * d2 + d3 * d3;
#pragma unroll
    for (int o = 32; o; o >>= 1) q += __shfl_xor(q, o, 64);
    if (lane == 0) red[w] = q;
    __syncthreads();
    float rs = rsqrtf((red[0] + red[1] + red[2] + red[3]) * (1.0f / DM) + 1e-6f);

    bool apply = !(iterp && iterp[0] == 0);
    f32x4 gv = *(const f32x4*)(gg + t * 4);
    f32x4 bv = *(const f32x4*)(bb + t * 4);
    us4 o;
    if (apply) {
        o[0] = f2b(d0 * rs * gv[0] + bv[0]);
        o[1] = f2b(d1 * rs * gv[1] + bv[1]);
        o[2] = f2b(d2 * rs * gv[2] + bv[2]);
        o[3] = f2b(d3 * rs * gv[3] + bv[3]);
    } else {
        o[0] = f2b(x[0]); o[1] = f2b(x[1]); o[2] = f2b(x[2]); o[3] = f2b(x[3]);
    }
    *(us4*)(outp + (size_t)row * DM + t * 4) = o;
}

// ---------------------------------------------------------------------------
__global__ __launch_bounds__(256) void softmax_mask(u16* __restrict__ sc)
{
    const int qrow = blockIdx.x;
    u16* rowp = sc + ((size_t)blockIdx.y << 20) + (size_t)qrow * SEQ;
    const int t = threadIdx.x, lane = t & 63, w = t >> 6;
    __shared__ float red[4];

    us4 r4 = *(const us4*)(rowp + t * 4);
    float v[4];
#pragma unroll
    for (int j = 0; j < 4; j++) {
        int k = t * 4 + j;
        v[j] = (k <= qrow) ? b2f(r4[j]) : 0.f;
    }
    float m = fmaxf(fmaxf(v[0], v[1]), fmaxf(v[2], v[3]));
#pragma unroll
    for (int o = 32; o; o >>= 1) m = fmaxf(m, __shfl_xor(m, o, 64));
    if (lane == 0) red[w] = m;
    __syncthreads();
    m = fmaxf(fmaxf(red[0], red[1]), fmaxf(red[2], red[3]));
    __syncthreads();
    float e0 = expf(v[0] - m), e1 = expf(v[1] - m), e2 = expf(v[2] - m), e3 = expf(v[3] - m);
    float s = e0 + e1 + e2 + e3;
#pragma unroll
    for (int o = 32; o; o >>= 1) s += __shfl_xor(s, o, 64);
    if (lane == 0) red[w] = s;
    __syncthreads();
    float inv = 1.0f / (red[0] + red[1] + red[2] + red[3]);
    us4 o;
    o[0] = f2b(e0 * inv); o[1] = f2b(e1 * inv); o[2] = f2b(e2 * inv); o[3] = f2b(e3 * inv);
    *(us4*)(rowp + t * 4) = o;
}

__global__ void transW(const float* __restrict__ W, u16* __restrict__ WT, int Kd, int Nd)
{
    __shared__ float tile[32][33];
    int bx = blockIdx.x << 5, by = blockIdx.y << 5;
    int tx = threadIdx.x, ty = threadIdx.y;
#pragma unroll
    for (int i = 0; i < 32; i += 8)
        tile[ty + i][tx] = W[(size_t)(by + ty + i) * Nd + bx + tx];
    __syncthreads();
#pragma unroll
    for (int i = 0; i < 32; i += 8)
        WT[(size_t)(bx + ty + i) * Kd + by + tx] = f2b(tile[tx][ty + i]);
}

__global__ void transV(const u16* __restrict__ Vb, u16* __restrict__ Vt)
{
    __shared__ u16 tile[32][33];
    int s0 = blockIdx.x << 5, d0 = blockIdx.y << 5, bh = blockIdx.z;
    int b = bh >> 4, h = bh & 15;
    int tx = threadIdx.x, ty = threadIdx.y;
#pragma unroll
    for (int i = 0; i < 32; i += 8)
        tile[ty + i][tx] = Vb[(size_t)((b << 10) + s0 + ty + i) * DM + (h << 6) + d0 + tx];
    __syncthreads();
#pragma unroll
    for (int i = 0; i < 32; i += 8)
        Vt[((size_t)bh << 16) + (size_t)(d0 + ty + i) * SEQ + s0 + tx] = tile[tx][ty + i];
}

__global__ __launch_bounds__(256) void resid_add(
    const u16* __restrict__ ctx, const float* __restrict__ x, float* __restrict__ outp)
{
    size_t i = ((size_t)blockIdx.x * 256 + threadIdx.x) * 4;
    us4 c = *(const us4*)(ctx + i);
    f32x4 xv = *(const f32x4*)(x + i);
    f32x4 o;
#pragma unroll
    for (int j = 0; j < 4; j++) o[j] = xv[j] + b2f(c[j]);
    *(f32x4*)(outp + i) = o;
}

// ---------------------------------------------------------------------------
extern "C" void kernel_launch(void* const* d_in, const int* in_sizes, int n_in,
                              void* d_out, int out_size, void* d_ws, size_t ws_size,
                              hipStream_t stream)
{
    const int* iter = (const int*)d_in[0];
    const float* x = (const float*)d_in[1];
    const float* Wq = (const float*)d_in[3];
    const float* bq = (const float*)d_in[4];
    const float* Wk = (const float*)d_in[5];
    const float* bk = (const float*)d_in[6];
    const float* Wv = (const float*)d_in[7];
    const float* bv = (const float*)d_in[8];
    const float* W1 = (const float*)d_in[9];
    const float* b1 = (const float*)d_in[10];
    const float* W2 = (const float*)d_in[11];
    const float* b2 = (const float*)d_in[12];
    const float* lag = (const float*)d_in[13];
    const float* lab = (const float*)d_in[14];
    const float* lfg = (const float*)d_in[15];
    const float* lfb = (const float*)d_in[16];
    float* out = (float*)d_out;

    char* ws = (char*)d_ws;
    size_t off = 0;
    auto alloc = [&](size_t bytes) {
        char* p = ws + off;
        off += (bytes + 255) & ~(size_t)255;
        return p;
    };
    u16* NXb = (u16*)alloc((size_t)MROWS * DM * 2);
    u16* Qb  = (u16*)alloc((size_t)MROWS * DM * 2);
    u16* Kb  = (u16*)alloc((size_t)MROWS * DM * 2);
    u16* Vb  = (u16*)alloc((size_t)MROWS * DM * 2);
    u16* ctx = (u16*)alloc((size_t)MROWS * DM * 2);
    u16* h2  = (u16*)alloc((size_t)MROWS * DFF * 2);
    u16* WqT = (u16*)alloc((size_t)DM * DM * 2);
    u16* WkT = (u16*)alloc((size_t)DM * DM * 2);
    u16* WvT = (u16*)alloc((size_t)DM * DM * 2);
    u16* W1T = (u16*)alloc((size_t)DM * DFF * 2);
    u16* W2T = (u16*)alloc((size_t)DM * DFF * 2);
    u16* Vt = NXb;
    u16* h1 = Qb;
    u16* scores = h2;

    dim3 tb(32, 8);
    transW<<<dim3(DM / 32, DM / 32), tb, 0, stream>>>(Wq, WqT, DM, DM);
    transW<<<dim3(DM / 32, DM / 32), tb, 0, stream>>>(Wk, WkT, DM, DM);
    transW<<<dim3(DM / 32, DM / 32), tb, 0, stream>>>(Wv, WvT, DM, DM);
    transW<<<dim3(DFF / 32, DM / 32), tb, 0, stream>>>(W1, W1T, DM, DFF);
    transW<<<dim3(DM / 32, DFF / 32), tb, 0, stream>>>(W2, W2T, DFF, DM);

    ln_bf16<<<MROWS, 256, 0, stream>>>(x, lag, lab, NXb, iter);

    // projections (2-phase 128x256): Q scaled by 1/sqrt(64)
    gemm2<128, 0><<<dim3(DM / 256, MROWS / 128), 512, 0, stream>>>(
        NXb, DM, WqT, DM, Qb, DM, bq, 0.125f, DM);
    gemm2<128, 0><<<dim3(DM / 256, MROWS / 128), 512, 0, stream>>>(
        NXb, DM, WkT, DM, Kb, DM, bk, 1.0f, DM);
    gemm2<128, 0><<<dim3(DM / 256, MROWS / 128), 512, 0, stream>>>(
        NXb, DM, WvT, DM, Vb, DM, bv, 1.0f, DM);

    transV<<<dim3(SEQ / 32, DH / 32, B_N * NH), tb, 0, stream>>>(Vb, Vt);

    // attention in 4 chunks of 32 heads (R1 kernels)
    for (int c = 0; c < 4; ++c) {
        const u16* Qc = Qb + (size_t)c * 2 * 1048576;
        const u16* Kc = Kb + (size_t)c * 2 * 1048576;
        gemm_bf16<128, 128, 2, 0><<<dim3(8, 8, 32), 256, 0, stream>>>(
            Qc, 1048576, 64, DM, Kc, 1048576, 64, DM,
            scores, 16777216, 1048576, SEQ, nullptr, 1.0f, DH);
        softmax_mask<<<dim3(SEQ, 32), 256, 0, stream>>>(scores);
        gemm_bf16<256, 64, 1, 0><<<dim3(1, 4, 32), 256, 0, stream>>>(
            scores, 16777216, 1048576, SEQ,
            Vt + (size_t)c * 2097152, 1048576, 65536, SEQ,
            (void*)(ctx + (size_t)c * 2097152), 1048576, 65536, DH,
            nullptr, 1.0f, SEQ);
    }

    resid_add<<<(MROWS * DM) / 1024, 256, 0, stream>>>(ctx, x, out);

    // FFN: h1 = LN(out); h2 = gelu(h1@W1+b1) [2ph 256^2];
    //      out += h2@W2+b2 [2ph 128x256]
    ln_bf16<<<MROWS, 256, 0, stream>>>(out, lfg, lfb, h1, nullptr);
    gemm2<256, 1><<<dim3(DFF / 256, MROWS / 256), 512, 0, stream>>>(
        h1, DM, W1T, DM, h2, DFF, b1, 1.0f, DM);
    gemm2<128, 2><<<dim3(DM / 256, MROWS / 128), 512, 0, stream>>>(
        h2, DFF, W2T, DFF, (void*)out, DM, b2, 1.0f, DFF);
}

// Round 7
// 521.783 us; speedup vs baseline: 1.5412x; 1.4461x over previous
//
#include <hip/hip_runtime.h>

// ---------------------------------------------------------------------------
// EncoderLayer: pre-LN attn (gated by iter!=0) + causal-mult-mask attention +
// residual + pre-LN FFN(GELU) + residual.  B=8 S=1024 D=1024 FF=4096 H=16 Dh=64
// R7: R6 flash attention with the V-staging swizzle bug fixed (granule bit 3
// was dropped: "& ~15" -> "& ~7"; keys 64-127 of every V tile were duplicates
// of keys 0-63). Everything else identical to R6.
// ---------------------------------------------------------------------------

#define B_N 8
#define SEQ 1024
#define DM 1024
#define DFF 4096
#define NH 16
#define DH 64
#define MROWS (B_N * SEQ) // 8192

typedef __attribute__((ext_vector_type(4))) float f32x4;
typedef __attribute__((ext_vector_type(8))) short short8;
typedef __attribute__((ext_vector_type(4))) unsigned short us4;
typedef unsigned short u16;

__device__ __forceinline__ float b2f(u16 u) { return __uint_as_float(((unsigned)u) << 16); }
__device__ __forceinline__ u16 f2b(float f) {
    unsigned u = __float_as_uint(f);
    return (u16)((u + 0x7fffu + ((u >> 16) & 1u)) >> 16); // RNE
}
__device__ __forceinline__ float gelu_f(float x) {
    float t = tanhf(0.7978845608028654f * (x + 0.044715f * x * x * x));
    return 0.5f * x * (1.0f + t);
}
__device__ __forceinline__ void async_cp16(const void* g, void* l) {
    __builtin_amdgcn_global_load_lds(
        (const __attribute__((address_space(1))) unsigned int*)g,
        (__attribute__((address_space(3))) unsigned int*)l, 16, 0, 0);
}

#define WAITV0() asm volatile("s_waitcnt vmcnt(0)" ::: "memory")
#define WAITL0()                                                                \
    asm volatile("s_waitcnt lgkmcnt(0)" ::: "memory");                          \
    __builtin_amdgcn_sched_barrier(0)

// ---------------------------------------------------------------------------
// Flash attention with multiplicative tril mask (masked scores = exactly 0,
// INCLUDED in softmax -- each masked key gets weight e^{-m}/Z, as in ref).
// Grid (8 q-tiles, 128 b*h). Block 256 thr = 4 waves; wave owns 32 q-rows.
// Q pre-scaled (1/8) in Qb. K-tile [128][64], V-tile (from Vt) [64][128],
// per-wave P [32][128] bf16 -- all XOR-swizzled (row&7)<<4, 64KB total.
// ---------------------------------------------------------------------------
__global__ __launch_bounds__(256, 2) void flash_attn(
    const u16* __restrict__ Qb, const u16* __restrict__ Kb,
    const u16* __restrict__ Vt, u16* __restrict__ ctx)
{
    constexpr float L2E = 1.44269504f;
    const int qt = blockIdx.x, bh = blockIdx.y;
    const int b = bh >> 4, h = bh & 15;
    const int tid = threadIdx.x, lane = tid & 63, w = tid >> 6;
    const int rr = lane & 15, qq = lane >> 4;

    __shared__ __align__(16) u16 smem[32768]; // 64KB
    char* Ksb = (char*)smem;                   // [128 keys][64 d]   16KB
    char* Vsb = (char*)(smem + 8192);          // [64 d][128 keys]   16KB
    char* Psb = (char*)(smem + 16384 + w * 4096); // per-wave [32][128] 8KB

    // hoisted Q A-frags: rows qt*128 + w*32 + mi*16 + rr, k = ks*32+qq*8
    short8 qf[2][2];
    {
        const size_t qr = (size_t)(b * 1024 + qt * 128 + w * 32 + rr);
#pragma unroll
        for (int mi = 0; mi < 2; ++mi)
#pragma unroll
            for (int ks = 0; ks < 2; ++ks)
                qf[mi][ks] = *(const short8*)(Qb + (qr + mi * 16) * DM + h * 64 + ks * 32 + qq * 8);
    }

    f32x4 oacc[2][4];
    float mrow[2][4], lrow[2][4];
#pragma unroll
    for (int mi = 0; mi < 2; ++mi)
#pragma unroll
        for (int j = 0; j < 4; ++j) { mrow[mi][j] = -1e30f; lrow[mi][j] = 0.f; }
#pragma unroll
    for (int mi = 0; mi < 2; ++mi)
#pragma unroll
        for (int ni = 0; ni < 4; ++ni)
#pragma unroll
            for (int e = 0; e < 4; ++e) oacc[mi][ni][e] = 0.f;

    const u16* Kbase = Kb + (size_t)b * 1024 * DM + h * 64;
    const u16* Vbase = Vt + ((size_t)bh << 16);
    const int sxr = (rr & 7) << 4;
    const int qbase = qt * 128 + w * 32 + qq * 4;

    for (int t = 0; t < 8; ++t) {
        // ---- stage K [128][64] (row 128B, 8 granules) and V [64][128] (row
        // 256B, 16 granules); source granule low3 ^= row&7 (matches read XOR)
#pragma unroll
        for (int i = 0; i < 4; ++i) {
            int g = tid + i * 256;
            int gs = (g & ~7) | ((g ^ (g >> 3)) & 7);
            async_cp16(Kbase + (size_t)(t * 128 + (gs >> 3)) * DM + ((gs & 7) << 3),
                       Ksb + g * 16);
        }
#pragma unroll
        for (int i = 0; i < 4; ++i) {
            int g = tid + i * 256;
            // FIX (R6 bug): preserve granule bit 3 -- "& ~7", not "& ~15".
            int gs = (g & ~7) | ((g ^ (g >> 4)) & 7);
            async_cp16(Vbase + (size_t)(gs >> 4) * SEQ + t * 128 + ((gs & 15) << 3),
                       Vsb + g * 16);
        }
        __syncthreads(); // drains vmcnt + barrier

        // ---- S = Q K^T : per wave 32 rows x 128 keys
        f32x4 sacc[2][8];
#pragma unroll
        for (int mi = 0; mi < 2; ++mi)
#pragma unroll
            for (int ni = 0; ni < 8; ++ni)
#pragma unroll
                for (int e = 0; e < 4; ++e) sacc[mi][ni][e] = 0.f;
#pragma unroll
        for (int ks = 0; ks < 2; ++ks)
#pragma unroll
            for (int ni = 0; ni < 8; ++ni) {
                short8 kf = *(const short8*)(Ksb + (rr + ni * 16) * 128 +
                                             ((ks * 64 + qq * 16) ^ sxr));
#pragma unroll
                for (int mi = 0; mi < 2; ++mi)
                    sacc[mi][ni] = __builtin_amdgcn_mfma_f32_16x16x32_bf16(
                        qf[mi][ks], kf, sacc[mi][ni], 0, 0, 0);
            }

        // ---- mask (k>q -> exactly 0) + row max (in-lane over ni, shfl over rr)
        const int kb0 = t * 128 + rr;
        float mx[2][4];
#pragma unroll
        for (int mi = 0; mi < 2; ++mi)
#pragma unroll
            for (int j = 0; j < 4; ++j) mx[mi][j] = -1e30f;
#pragma unroll
        for (int mi = 0; mi < 2; ++mi)
#pragma unroll
            for (int ni = 0; ni < 8; ++ni)
#pragma unroll
                for (int j = 0; j < 4; ++j) {
                    float sv = (kb0 + ni * 16 <= qbase + mi * 16 + j) ? sacc[mi][ni][j] : 0.f;
                    sacc[mi][ni][j] = sv;
                    mx[mi][j] = fmaxf(mx[mi][j], sv);
                }
#pragma unroll
        for (int mi = 0; mi < 2; ++mi)
#pragma unroll
            for (int j = 0; j < 4; ++j) {
                float v = mx[mi][j];
#pragma unroll
                for (int o = 1; o < 16; o <<= 1) v = fmaxf(v, __shfl_xor(v, o, 64));
                mx[mi][j] = v;
            }

        // ---- online rescale + P = exp(S-m) -> bf16 LDS (swizzled), row sums
        float rs[2][4];
#pragma unroll
        for (int mi = 0; mi < 2; ++mi)
#pragma unroll
            for (int j = 0; j < 4; ++j) {
                float mn = fmaxf(mrow[mi][j], mx[mi][j]);
                float sc = exp2f((mrow[mi][j] - mn) * L2E);
                mrow[mi][j] = mn;
                lrow[mi][j] *= sc;
                rs[mi][j] = 0.f;
#pragma unroll
                for (int ni = 0; ni < 4; ++ni) oacc[mi][ni][j] *= sc;
            }
#pragma unroll
        for (int mi = 0; mi < 2; ++mi)
#pragma unroll
            for (int ni = 0; ni < 8; ++ni)
#pragma unroll
                for (int j = 0; j < 4; ++j) {
                    float p = exp2f((sacc[mi][ni][j] - mrow[mi][j]) * L2E);
                    rs[mi][j] += p;
                    const int prow = mi * 16 + qq * 4 + j;
                    *(u16*)(Psb + prow * 256 +
                            (((rr + ni * 16) * 2) ^ ((prow & 7) << 4))) = f2b(p);
                }
#pragma unroll
        for (int mi = 0; mi < 2; ++mi)
#pragma unroll
            for (int j = 0; j < 4; ++j) {
                float v = rs[mi][j];
#pragma unroll
                for (int o = 1; o < 16; o <<= 1) v += __shfl_xor(v, o, 64);
                lrow[mi][j] += v;
            }

        WAITL0(); // own-wave P writes visible before P reads (rule #18 fence)

        // ---- O += P @ V : P A-frags [32][128], V B-frags [64 d][128 keys]
#pragma unroll
        for (int kk = 0; kk < 4; ++kk) {
            short8 pa[2], pv[4];
#pragma unroll
            for (int mi = 0; mi < 2; ++mi)
                pa[mi] = *(const short8*)(Psb + (mi * 16 + rr) * 256 +
                                          ((kk * 64 + qq * 16) ^ sxr));
#pragma unroll
            for (int ni = 0; ni < 4; ++ni)
                pv[ni] = *(const short8*)(Vsb + (rr + ni * 16) * 256 +
                                          ((kk * 64 + qq * 16) ^ sxr));
#pragma unroll
            for (int mi = 0; mi < 2; ++mi)
#pragma unroll
                for (int ni = 0; ni < 4; ++ni)
                    oacc[mi][ni] = __builtin_amdgcn_mfma_f32_16x16x32_bf16(
                        pa[mi], pv[ni], oacc[mi][ni], 0, 0, 0);
        }
        __syncthreads(); // all waves done with Ks/Vs before next stage
    }

    // ---- epilogue: O/l -> ctx [bh][s][d]
    float inv[2][4];
#pragma unroll
    for (int mi = 0; mi < 2; ++mi)
#pragma unroll
        for (int j = 0; j < 4; ++j) inv[mi][j] = 1.0f / lrow[mi][j];
    u16* cb = ctx + ((size_t)bh << 16);
#pragma unroll
    for (int mi = 0; mi < 2; ++mi)
#pragma unroll
        for (int ni = 0; ni < 4; ++ni)
#pragma unroll
            for (int j = 0; j < 4; ++j) {
                const int srow = qt * 128 + w * 32 + mi * 16 + qq * 4 + j;
                cb[(size_t)srow * 64 + rr + ni * 16] = f2b(oacc[mi][ni][j] * inv[mi][j]);
            }
}

// ---------------------------------------------------------------------------
// 2-phase GEMM (R5, unchanged): C[m][n] = (sum_k A[m][k]*Bt[n][k]+bias)*scale
// ---------------------------------------------------------------------------
template <int BM, int EPI>
__global__ __launch_bounds__(512, 2) void gemm2(
    const u16* __restrict__ A, int lda,
    const u16* __restrict__ Bt, int ldb,
    void* __restrict__ C, int ldc,
    const float* __restrict__ bias, float scale, int K)
{
    constexpr int BN = 256;
    constexpr int MF = BM / 32;
    constexpr int MFH = MF / 2;
    constexpr int ABYT = BM * 128;
    constexpr int BBYT = BN * 128;
    constexpr int LA = ABYT / 8192;
    constexpr int LB = BBYT / 8192;
    constexpr int BUFB = ABYT + BBYT;
    __shared__ __align__(16) char lds[2 * BUFB];

    const int tid = threadIdx.x;
    const int lane = tid & 63;
    const int w = tid >> 6;
    const int wm = w >> 2, wn = w & 3;
    const int rr = lane & 15, qq = lane >> 4;

    const int nwg = gridDim.x * gridDim.y;
    int flat = blockIdx.y * gridDim.x + blockIdx.x;
    flat = (flat & 7) * (nwg >> 3) + (flat >> 3);
    const int m0 = (flat / gridDim.x) * BM;
    const int n0 = (flat % gridDim.x) * BN;

    const int s = (rr & 7) << 4;
    const int swq = (qq * 16) ^ (s & 48);
    const int ksx[2] = { s & 64, 64 ^ (s & 64) };
    const int aoff = (wm * (BM / 2) + rr) * 128 + swq;
    const int boff = ABYT + (wn * 64 + rr) * 128 + swq;

    f32x4 acc[MF][4];
#pragma unroll
    for (int i = 0; i < MF; i++)
#pragma unroll
        for (int j = 0; j < 4; j++)
#pragma unroll
            for (int e = 0; e < 4; e++) acc[i][j][e] = 0.f;

    auto stage = [&](int nb, int t) {
        char* dst = lds + nb * BUFB;
#pragma unroll
        for (int i = 0; i < LA; ++i) {
            int g = tid + i * 512;
            int gs = (g & ~7) | ((g ^ (g >> 3)) & 7);
            async_cp16(A + (size_t)(m0 + (gs >> 3)) * lda + (t << 6) + ((gs & 7) << 3),
                       dst + g * 16);
        }
#pragma unroll
        for (int i = 0; i < LB; ++i) {
            int g = tid + i * 512;
            int gs = (g & ~7) | ((g ^ (g >> 3)) & 7);
            async_cp16(Bt + (size_t)(n0 + (gs >> 3)) * ldb + (t << 6) + ((gs & 7) << 3),
                       dst + ABYT + g * 16);
        }
    };

    auto ktile = [&](const char* buf) {
        short8 bfr[4][2], afr[MFH][2];
#pragma unroll
        for (int f = 0; f < 4; ++f)
#pragma unroll
            for (int ks = 0; ks < 2; ++ks)
                bfr[f][ks] = *(const short8*)(buf + boff + f * 2048 + ksx[ks]);
#pragma unroll
        for (int m2 = 0; m2 < MFH; ++m2)
#pragma unroll
            for (int ks = 0; ks < 2; ++ks)
                afr[m2][ks] = *(const short8*)(buf + aoff + m2 * 2048 + ksx[ks]);
        WAITL0();
        __builtin_amdgcn_s_setprio(1);
#pragma unroll
        for (int ks = 0; ks < 2; ++ks)
#pragma unroll
            for (int m2 = 0; m2 < MFH; ++m2)
#pragma unroll
                for (int f = 0; f < 4; ++f)
                    acc[m2][f] = __builtin_amdgcn_mfma_f32_16x16x32_bf16(
                        afr[m2][ks], bfr[f][ks], acc[m2][f], 0, 0, 0);
#pragma unroll
        for (int m2 = 0; m2 < MFH; ++m2)
#pragma unroll
            for (int ks = 0; ks < 2; ++ks)
                afr[m2][ks] = *(const short8*)(buf + aoff + (MFH + m2) * 2048 + ksx[ks]);
        WAITL0();
#pragma unroll
        for (int ks = 0; ks < 2; ++ks)
#pragma unroll
            for (int m2 = 0; m2 < MFH; ++m2)
#pragma unroll
                for (int f = 0; f < 4; ++f)
                    acc[MFH + m2][f] = __builtin_amdgcn_mfma_f32_16x16x32_bf16(
                        afr[m2][ks], bfr[f][ks], acc[MFH + m2][f], 0, 0, 0);
        __builtin_amdgcn_s_setprio(0);
    };

    stage(0, 0);
    WAITV0();
    __builtin_amdgcn_s_barrier();

    const int NT = K >> 6;
    for (int t = 0; t < NT - 1; ++t) {
        const int cur = t & 1;
        stage(1 - cur, t + 1);
        ktile(lds + cur * BUFB);
        WAITV0();
        __builtin_amdgcn_s_barrier();
    }
    ktile(lds + ((NT - 1) & 1) * BUFB);

    const int ccol = n0 + wn * 64 + rr;
    const int crow = m0 + wm * (BM / 2) + qq * 4;
#pragma unroll
    for (int mi = 0; mi < MF; ++mi) {
#pragma unroll
        for (int ni = 0; ni < 4; ++ni) {
            const int colg = ccol + ni * 16;
            const float bv = bias ? bias[colg] : 0.f;
#pragma unroll
            for (int j = 0; j < 4; ++j) {
                const int rowg = crow + mi * 16 + j;
                float v = (acc[mi][ni][j] + bv) * scale;
                size_t idx = (size_t)rowg * ldc + colg;
                if (EPI == 1) v = gelu_f(v);
                if (EPI == 2) ((float*)C)[idx] += v;
                else ((u16*)C)[idx] = f2b(v);
            }
        }
    }
}

// ---------------------------------------------------------------------------
__global__ __launch_bounds__(256) void ln_bf16(
    const float* __restrict__ in, const float* __restrict__ gg,
    const float* __restrict__ bb, u16* __restrict__ outp,
    const int* __restrict__ iterp)
{
    const int row = blockIdx.x;
    const int t = threadIdx.x;
    const int lane = t & 63, w = t >> 6;
    const float* r = in + (size_t)row * DM;
    f32x4 x = *(const f32x4*)(r + t * 4);
    __shared__ float red[4];

    float s = x[0] + x[1] + x[2] + x[3];
#pragma unroll
    for (int o = 32; o; o >>= 1) s += __shfl_xor(s, o, 64);
    if (lane == 0) red[w] = s;
    __syncthreads();
    float mu = (red[0] + red[1] + red[2] + red[3]) * (1.0f / DM);
    __syncthreads();

    float d0 = x[0] - mu, d1 = x[1] - mu, d2 = x[2] - mu, d3 = x[3] - mu;
    float q = d0 * d0 + d1 * d1 + d2 * d2 + d3 * d3;
#pragma unroll
    for (int o = 32; o; o >>= 1) q += __shfl_xor(q, o, 64);
    if (lane == 0) red[w] = q;
    __syncthreads();
    float rs = rsqrtf((red[0] + red[1] + red[2] + red[3]) * (1.0f / DM) + 1e-6f);

    bool apply = !(iterp && iterp[0] == 0);
    f32x4 gv = *(const f32x4*)(gg + t * 4);
    f32x4 bv = *(const f32x4*)(bb + t * 4);
    us4 o;
    if (apply) {
        o[0] = f2b(d0 * rs * gv[0] + bv[0]);
        o[1] = f2b(d1 * rs * gv[1] + bv[1]);
        o[2] = f2b(d2 * rs * gv[2] + bv[2]);
        o[3] = f2b(d3 * rs * gv[3] + bv[3]);
    } else {
        o[0] = f2b(x[0]); o[1] = f2b(x[1]); o[2] = f2b(x[2]); o[3] = f2b(x[3]);
    }
    *(us4*)(outp + (size_t)row * DM + t * 4) = o;
}

__global__ void transW(const float* __restrict__ W, u16* __restrict__ WT, int Kd, int Nd)
{
    __shared__ float tile[32][33];
    int bx = blockIdx.x << 5, by = blockIdx.y << 5;
    int tx = threadIdx.x, ty = threadIdx.y;
#pragma unroll
    for (int i = 0; i < 32; i += 8)
        tile[ty + i][tx] = W[(size_t)(by + ty + i) * Nd + bx + tx];
    __syncthreads();
#pragma unroll
    for (int i = 0; i < 32; i += 8)
        WT[(size_t)(bx + ty + i) * Kd + by + tx] = f2b(tile[tx][ty + i]);
}

__global__ void transV(const u16* __restrict__ Vb, u16* __restrict__ Vt)
{
    __shared__ u16 tile[32][33];
    int s0 = blockIdx.x << 5, d0 = blockIdx.y << 5, bh = blockIdx.z;
    int b = bh >> 4, h = bh & 15;
    int tx = threadIdx.x, ty = threadIdx.y;
#pragma unroll
    for (int i = 0; i < 32; i += 8)
        tile[ty + i][tx] = Vb[(size_t)((b << 10) + s0 + ty + i) * DM + (h << 6) + d0 + tx];
    __syncthreads();
#pragma unroll
    for (int i = 0; i < 32; i += 8)
        Vt[((size_t)bh << 16) + (size_t)(d0 + ty + i) * SEQ + s0 + tx] = tile[tx][ty + i];
}

__global__ __launch_bounds__(256) void resid_add(
    const u16* __restrict__ ctx, const float* __restrict__ x, float* __restrict__ outp)
{
    size_t i = ((size_t)blockIdx.x * 256 + threadIdx.x) * 4;
    us4 c = *(const us4*)(ctx + i);
    f32x4 xv = *(const f32x4*)(x + i);
    f32x4 o;
#pragma unroll
    for (int j = 0; j < 4; j++) o[j] = xv[j] + b2f(c[j]);
    *(f32x4*)(outp + i) = o;
}

// ---------------------------------------------------------------------------
extern "C" void kernel_launch(void* const* d_in, const int* in_sizes, int n_in,
                              void* d_out, int out_size, void* d_ws, size_t ws_size,
                              hipStream_t stream)
{
    const int* iter = (const int*)d_in[0];
    const float* x = (const float*)d_in[1];
    const float* Wq = (const float*)d_in[3];
    const float* bq = (const float*)d_in[4];
    const float* Wk = (const float*)d_in[5];
    const float* bk = (const float*)d_in[6];
    const float* Wv = (const float*)d_in[7];
    const float* bv = (const float*)d_in[8];
    const float* W1 = (const float*)d_in[9];
    const float* b1 = (const float*)d_in[10];
    const float* W2 = (const float*)d_in[11];
    const float* b2 = (const float*)d_in[12];
    const float* lag = (const float*)d_in[13];
    const float* lab = (const float*)d_in[14];
    const float* lfg = (const float*)d_in[15];
    const float* lfb = (const float*)d_in[16];
    float* out = (float*)d_out;

    char* ws = (char*)d_ws;
    size_t off = 0;
    auto alloc = [&](size_t bytes) {
        char* p = ws + off;
        off += (bytes + 255) & ~(size_t)255;
        return p;
    };
    u16* NXb = (u16*)alloc((size_t)MROWS * DM * 2);
    u16* Qb  = (u16*)alloc((size_t)MROWS * DM * 2);
    u16* Kb  = (u16*)alloc((size_t)MROWS * DM * 2);
    u16* Vb  = (u16*)alloc((size_t)MROWS * DM * 2);
    u16* ctx = (u16*)alloc((size_t)MROWS * DM * 2);
    u16* h2  = (u16*)alloc((size_t)MROWS * DFF * 2);
    u16* WqT = (u16*)alloc((size_t)DM * DM * 2);
    u16* WkT = (u16*)alloc((size_t)DM * DM * 2);
    u16* WvT = (u16*)alloc((size_t)DM * DM * 2);
    u16* W1T = (u16*)alloc((size_t)DM * DFF * 2);
    u16* W2T = (u16*)alloc((size_t)DM * DFF * 2);
    u16* Vt = NXb;  // alias: NXb dead after projections
    u16* h1 = Qb;   // alias: Qb dead after attention

    dim3 tb(32, 8);
    transW<<<dim3(DM / 32, DM / 32), tb, 0, stream>>>(Wq, WqT, DM, DM);
    transW<<<dim3(DM / 32, DM / 32), tb, 0, stream>>>(Wk, WkT, DM, DM);
    transW<<<dim3(DM / 32, DM / 32), tb, 0, stream>>>(Wv, WvT, DM, DM);
    transW<<<dim3(DFF / 32, DM / 32), tb, 0, stream>>>(W1, W1T, DM, DFF);
    transW<<<dim3(DM / 32, DFF / 32), tb, 0, stream>>>(W2, W2T, DFF, DM);

    ln_bf16<<<MROWS, 256, 0, stream>>>(x, lag, lab, NXb, iter);

    // projections (2-phase 128x256): Q scaled by 1/sqrt(64)
    gemm2<128, 0><<<dim3(DM / 256, MROWS / 128), 512, 0, stream>>>(
        NXb, DM, WqT, DM, Qb, DM, bq, 0.125f, DM);
    gemm2<128, 0><<<dim3(DM / 256, MROWS / 128), 512, 0, stream>>>(
        NXb, DM, WkT, DM, Kb, DM, bk, 1.0f, DM);
    gemm2<128, 0><<<dim3(DM / 256, MROWS / 128), 512, 0, stream>>>(
        NXb, DM, WvT, DM, Vb, DM, bv, 1.0f, DM);

    transV<<<dim3(SEQ / 32, DH / 32, B_N * NH), tb, 0, stream>>>(Vb, Vt);

    // fused flash attention (replaces QK gemm + softmax + PV gemm x4 chunks)
    flash_attn<<<dim3(SEQ / 128, B_N * NH), 256, 0, stream>>>(Qb, Kb, Vt, ctx);

    resid_add<<<(MROWS * DM) / 1024, 256, 0, stream>>>(ctx, x, out);

    // FFN: h1 = LN(out); h2 = gelu(h1@W1+b1); out += h2@W2+b2
    ln_bf16<<<MROWS, 256, 0, stream>>>(out, lfg, lfb, h1, nullptr);
    gemm2<256, 1><<<dim3(DFF / 256, MROWS / 256), 512, 0, stream>>>(
        h1, DM, W1T, DM, h2, DFF, b1, 1.0f, DM);
    gemm2<128, 2><<<dim3(DM / 256, MROWS / 128), 512, 0, stream>>>(
        h2, DFF, W2T, DFF, (void*)out, DM, b2, 1.0f, DFF);
}

// Round 8
// 466.256 us; speedup vs baseline: 1.7247x; 1.1191x over previous
//
#include <hip/hip_runtime.h>

// ---------------------------------------------------------------------------
// EncoderLayer: pre-LN attn (gated by iter!=0) + causal-mult-mask attention +
// residual + pre-LN FFN(GELU) + residual.  B=8 S=1024 D=1024 FF=4096 H=16 Dh=64
// R8: new gemm3 = m97-style high-TLP GEMM (128^2 tile, BK=64, single-buffered
// 32KB LDS -> 3 blocks/CU for implicit inter-block overlap) + R5's verified
// 0-conflict swizzle. Used for QKV projections + FFN1. FFN2 kept on gemm2
// (1 block/CU, 2-phase) as the in-launch A/B control. Flash attention from R7.
// ---------------------------------------------------------------------------

#define B_N 8
#define SEQ 1024
#define DM 1024
#define DFF 4096
#define NH 16
#define DH 64
#define MROWS (B_N * SEQ) // 8192

typedef __attribute__((ext_vector_type(4))) float f32x4;
typedef __attribute__((ext_vector_type(8))) short short8;
typedef __attribute__((ext_vector_type(4))) unsigned short us4;
typedef unsigned short u16;

__device__ __forceinline__ float b2f(u16 u) { return __uint_as_float(((unsigned)u) << 16); }
__device__ __forceinline__ u16 f2b(float f) {
    unsigned u = __float_as_uint(f);
    return (u16)((u + 0x7fffu + ((u >> 16) & 1u)) >> 16); // RNE
}
__device__ __forceinline__ float gelu_f(float x) {
    float t = tanhf(0.7978845608028654f * (x + 0.044715f * x * x * x));
    return 0.5f * x * (1.0f + t);
}
__device__ __forceinline__ void async_cp16(const void* g, void* l) {
    __builtin_amdgcn_global_load_lds(
        (const __attribute__((address_space(1))) unsigned int*)g,
        (__attribute__((address_space(3))) unsigned int*)l, 16, 0, 0);
}

#define WAITV0() asm volatile("s_waitcnt vmcnt(0)" ::: "memory")
#define WAITL0()                                                                \
    asm volatile("s_waitcnt lgkmcnt(0)" ::: "memory");                          \
    __builtin_amdgcn_sched_barrier(0)

// ---------------------------------------------------------------------------
// gemm3: m97-style high-TLP GEMM.  C[m][n] = (sum A[m][k]*Bt[n][k]+bias)*scale
// 256 thr = 4 waves (2x2), tile 128x128, BK=64, single-buffered 32KB LDS ->
// 3 blocks/CU (implicit inter-block overlap hides the stage drain, m114).
// LDS swizzle: in-row byte ^= ((row&7)<<4) on read; source granule low3 ^=
// row&7 on stage (R3-R5 verified: 0 bank conflicts).
// EPI: 0 = bf16 out; 1 = bf16 GELU out; 2 = fp32 C += v
// ---------------------------------------------------------------------------
template <int EPI>
__global__ __launch_bounds__(256, 3) void gemm3(
    const u16* __restrict__ A, int lda,
    const u16* __restrict__ Bt, int ldb,
    void* __restrict__ C, int ldc,
    const float* __restrict__ bias, float scale, int K)
{
    __shared__ __align__(16) char lds[32768]; // A [128][128B] + B [128][128B]

    const int tid = threadIdx.x;
    const int lane = tid & 63;
    const int w = tid >> 6;
    const int wm = w >> 1, wn = w & 1;
    const int rr = lane & 15, qq = lane >> 4;
    const int m0 = blockIdx.y * 128, n0 = blockIdx.x * 128;

    const int s = (rr & 7) << 4;
    const int swq = (qq * 16) ^ (s & 48);
    const int ksx[2] = { s & 64, 64 ^ (s & 64) };
    const int aoff = (wm * 64 + rr) * 128 + swq;
    const int boff = 16384 + (wn * 64 + rr) * 128 + swq;

    f32x4 acc[4][4];
#pragma unroll
    for (int i = 0; i < 4; i++)
#pragma unroll
        for (int j = 0; j < 4; j++)
#pragma unroll
            for (int e = 0; e < 4; e++) acc[i][j][e] = 0.f;

    const int NT = K >> 6;
    for (int t = 0; t < NT; ++t) {
        // stage A[128][64] + B[128][64] (16KB each); inverse-swizzled source
#pragma unroll
        for (int i = 0; i < 4; ++i) {
            int g = tid + i * 256;
            int gs = (g & ~7) | ((g ^ (g >> 3)) & 7);
            async_cp16(A + (size_t)(m0 + (gs >> 3)) * lda + (t << 6) + ((gs & 7) << 3),
                       lds + g * 16);
        }
#pragma unroll
        for (int i = 0; i < 4; ++i) {
            int g = tid + i * 256;
            int gs = (g & ~7) | ((g ^ (g >> 3)) & 7);
            async_cp16(Bt + (size_t)(n0 + (gs >> 3)) * ldb + (t << 6) + ((gs & 7) << 3),
                       lds + 16384 + g * 16);
        }
        __syncthreads(); // drains vmcnt(0): tile ready

        short8 af[4][2], bfr[4][2];
#pragma unroll
        for (int mi = 0; mi < 4; ++mi)
#pragma unroll
            for (int ks = 0; ks < 2; ++ks)
                af[mi][ks] = *(const short8*)(lds + aoff + mi * 2048 + ksx[ks]);
#pragma unroll
        for (int ni = 0; ni < 4; ++ni)
#pragma unroll
            for (int ks = 0; ks < 2; ++ks)
                bfr[ni][ks] = *(const short8*)(lds + boff + ni * 2048 + ksx[ks]);
#pragma unroll
        for (int ks = 0; ks < 2; ++ks)
#pragma unroll
            for (int mi = 0; mi < 4; ++mi)
#pragma unroll
                for (int ni = 0; ni < 4; ++ni)
                    acc[mi][ni] = __builtin_amdgcn_mfma_f32_16x16x32_bf16(
                        af[mi][ks], bfr[ni][ks], acc[mi][ni], 0, 0, 0);
        __syncthreads(); // all waves done reading before next stage
    }

    // epilogue: C/D layout col=lane&15, row=(lane>>4)*4+j
    const int ccol = n0 + wn * 64 + rr;
    const int crow = m0 + wm * 64 + qq * 4;
#pragma unroll
    for (int mi = 0; mi < 4; ++mi) {
#pragma unroll
        for (int ni = 0; ni < 4; ++ni) {
            const int colg = ccol + ni * 16;
            const float bv = bias ? bias[colg] : 0.f;
#pragma unroll
            for (int j = 0; j < 4; ++j) {
                const int rowg = crow + mi * 16 + j;
                float v = (acc[mi][ni][j] + bv) * scale;
                size_t idx = (size_t)rowg * ldc + colg;
                if (EPI == 1) v = gelu_f(v);
                if (EPI == 2) ((float*)C)[idx] += v;
                else ((u16*)C)[idx] = f2b(v);
            }
        }
    }
}

// ---------------------------------------------------------------------------
// gemm2 (R5, kept as FFN2 control): 2-phase, 8 waves, 128KB LDS, 1 block/CU.
// ---------------------------------------------------------------------------
template <int BM, int EPI>
__global__ __launch_bounds__(512, 2) void gemm2(
    const u16* __restrict__ A, int lda,
    const u16* __restrict__ Bt, int ldb,
    void* __restrict__ C, int ldc,
    const float* __restrict__ bias, float scale, int K)
{
    constexpr int BN = 256;
    constexpr int MF = BM / 32;
    constexpr int MFH = MF / 2;
    constexpr int ABYT = BM * 128;
    constexpr int BBYT = BN * 128;
    constexpr int LA = ABYT / 8192;
    constexpr int LB = BBYT / 8192;
    constexpr int BUFB = ABYT + BBYT;
    __shared__ __align__(16) char lds[2 * BUFB];

    const int tid = threadIdx.x;
    const int lane = tid & 63;
    const int w = tid >> 6;
    const int wm = w >> 2, wn = w & 3;
    const int rr = lane & 15, qq = lane >> 4;

    const int nwg = gridDim.x * gridDim.y;
    int flat = blockIdx.y * gridDim.x + blockIdx.x;
    flat = (flat & 7) * (nwg >> 3) + (flat >> 3);
    const int m0 = (flat / gridDim.x) * BM;
    const int n0 = (flat % gridDim.x) * BN;

    const int s = (rr & 7) << 4;
    const int swq = (qq * 16) ^ (s & 48);
    const int ksx[2] = { s & 64, 64 ^ (s & 64) };
    const int aoff = (wm * (BM / 2) + rr) * 128 + swq;
    const int boff = ABYT + (wn * 64 + rr) * 128 + swq;

    f32x4 acc[MF][4];
#pragma unroll
    for (int i = 0; i < MF; i++)
#pragma unroll
        for (int j = 0; j < 4; j++)
#pragma unroll
            for (int e = 0; e < 4; e++) acc[i][j][e] = 0.f;

    auto stage = [&](int nb, int t) {
        char* dst = lds + nb * BUFB;
#pragma unroll
        for (int i = 0; i < LA; ++i) {
            int g = tid + i * 512;
            int gs = (g & ~7) | ((g ^ (g >> 3)) & 7);
            async_cp16(A + (size_t)(m0 + (gs >> 3)) * lda + (t << 6) + ((gs & 7) << 3),
                       dst + g * 16);
        }
#pragma unroll
        for (int i = 0; i < LB; ++i) {
            int g = tid + i * 512;
            int gs = (g & ~7) | ((g ^ (g >> 3)) & 7);
            async_cp16(Bt + (size_t)(n0 + (gs >> 3)) * ldb + (t << 6) + ((gs & 7) << 3),
                       dst + ABYT + g * 16);
        }
    };

    auto ktile = [&](const char* buf) {
        short8 bfr[4][2], afr[MFH][2];
#pragma unroll
        for (int f = 0; f < 4; ++f)
#pragma unroll
            for (int ks = 0; ks < 2; ++ks)
                bfr[f][ks] = *(const short8*)(buf + boff + f * 2048 + ksx[ks]);
#pragma unroll
        for (int m2 = 0; m2 < MFH; ++m2)
#pragma unroll
            for (int ks = 0; ks < 2; ++ks)
                afr[m2][ks] = *(const short8*)(buf + aoff + m2 * 2048 + ksx[ks]);
        WAITL0();
        __builtin_amdgcn_s_setprio(1);
#pragma unroll
        for (int ks = 0; ks < 2; ++ks)
#pragma unroll
            for (int m2 = 0; m2 < MFH; ++m2)
#pragma unroll
                for (int f = 0; f < 4; ++f)
                    acc[m2][f] = __builtin_amdgcn_mfma_f32_16x16x32_bf16(
                        afr[m2][ks], bfr[f][ks], acc[m2][f], 0, 0, 0);
#pragma unroll
        for (int m2 = 0; m2 < MFH; ++m2)
#pragma unroll
            for (int ks = 0; ks < 2; ++ks)
                afr[m2][ks] = *(const short8*)(buf + aoff + (MFH + m2) * 2048 + ksx[ks]);
        WAITL0();
#pragma unroll
        for (int ks = 0; ks < 2; ++ks)
#pragma unroll
            for (int m2 = 0; m2 < MFH; ++m2)
#pragma unroll
                for (int f = 0; f < 4; ++f)
                    acc[MFH + m2][f] = __builtin_amdgcn_mfma_f32_16x16x32_bf16(
                        afr[m2][ks], bfr[f][ks], acc[MFH + m2][f], 0, 0, 0);
        __builtin_amdgcn_s_setprio(0);
    };

    stage(0, 0);
    WAITV0();
    __builtin_amdgcn_s_barrier();

    const int NT = K >> 6;
    for (int t = 0; t < NT - 1; ++t) {
        const int cur = t & 1;
        stage(1 - cur, t + 1);
        ktile(lds + cur * BUFB);
        WAITV0();
        __builtin_amdgcn_s_barrier();
    }
    ktile(lds + ((NT - 1) & 1) * BUFB);

    const int ccol = n0 + wn * 64 + rr;
    const int crow = m0 + wm * (BM / 2) + qq * 4;
#pragma unroll
    for (int mi = 0; mi < MF; ++mi) {
#pragma unroll
        for (int ni = 0; ni < 4; ++ni) {
            const int colg = ccol + ni * 16;
            const float bv = bias ? bias[colg] : 0.f;
#pragma unroll
            for (int j = 0; j < 4; ++j) {
                const int rowg = crow + mi * 16 + j;
                float v = (acc[mi][ni][j] + bv) * scale;
                size_t idx = (size_t)rowg * ldc + colg;
                if (EPI == 1) v = gelu_f(v);
                if (EPI == 2) ((float*)C)[idx] += v;
                else ((u16*)C)[idx] = f2b(v);
            }
        }
    }
}

// ---------------------------------------------------------------------------
// Flash attention (R7, verified): multiplicative tril mask, masked scores = 0
// and included in softmax.  4 waves x 32 q-rows, KV-tile 128, 64KB LDS.
// ---------------------------------------------------------------------------
__global__ __launch_bounds__(256, 2) void flash_attn(
    const u16* __restrict__ Qb, const u16* __restrict__ Kb,
    const u16* __restrict__ Vt, u16* __restrict__ ctx)
{
    constexpr float L2E = 1.44269504f;
    const int qt = blockIdx.x, bh = blockIdx.y;
    const int b = bh >> 4, h = bh & 15;
    const int tid = threadIdx.x, lane = tid & 63, w = tid >> 6;
    const int rr = lane & 15, qq = lane >> 4;

    __shared__ __align__(16) u16 smem[32768]; // 64KB
    char* Ksb = (char*)smem;
    char* Vsb = (char*)(smem + 8192);
    char* Psb = (char*)(smem + 16384 + w * 4096);

    short8 qf[2][2];
    {
        const size_t qr = (size_t)(b * 1024 + qt * 128 + w * 32 + rr);
#pragma unroll
        for (int mi = 0; mi < 2; ++mi)
#pragma unroll
            for (int ks = 0; ks < 2; ++ks)
                qf[mi][ks] = *(const short8*)(Qb + (qr + mi * 16) * DM + h * 64 + ks * 32 + qq * 8);
    }

    f32x4 oacc[2][4];
    float mrow[2][4], lrow[2][4];
#pragma unroll
    for (int mi = 0; mi < 2; ++mi)
#pragma unroll
        for (int j = 0; j < 4; ++j) { mrow[mi][j] = -1e30f; lrow[mi][j] = 0.f; }
#pragma unroll
    for (int mi = 0; mi < 2; ++mi)
#pragma unroll
        for (int ni = 0; ni < 4; ++ni)
#pragma unroll
            for (int e = 0; e < 4; ++e) oacc[mi][ni][e] = 0.f;

    const u16* Kbase = Kb + (size_t)b * 1024 * DM + h * 64;
    const u16* Vbase = Vt + ((size_t)bh << 16);
    const int sxr = (rr & 7) << 4;
    const int qbase = qt * 128 + w * 32 + qq * 4;

    for (int t = 0; t < 8; ++t) {
#pragma unroll
        for (int i = 0; i < 4; ++i) {
            int g = tid + i * 256;
            int gs = (g & ~7) | ((g ^ (g >> 3)) & 7);
            async_cp16(Kbase + (size_t)(t * 128 + (gs >> 3)) * DM + ((gs & 7) << 3),
                       Ksb + g * 16);
        }
#pragma unroll
        for (int i = 0; i < 4; ++i) {
            int g = tid + i * 256;
            int gs = (g & ~7) | ((g ^ (g >> 4)) & 7);
            async_cp16(Vbase + (size_t)(gs >> 4) * SEQ + t * 128 + ((gs & 15) << 3),
                       Vsb + g * 16);
        }
        __syncthreads();

        f32x4 sacc[2][8];
#pragma unroll
        for (int mi = 0; mi < 2; ++mi)
#pragma unroll
            for (int ni = 0; ni < 8; ++ni)
#pragma unroll
                for (int e = 0; e < 4; ++e) sacc[mi][ni][e] = 0.f;
#pragma unroll
        for (int ks = 0; ks < 2; ++ks)
#pragma unroll
            for (int ni = 0; ni < 8; ++ni) {
                short8 kf = *(const short8*)(Ksb + (rr + ni * 16) * 128 +
                                             ((ks * 64 + qq * 16) ^ sxr));
#pragma unroll
                for (int mi = 0; mi < 2; ++mi)
                    sacc[mi][ni] = __builtin_amdgcn_mfma_f32_16x16x32_bf16(
                        qf[mi][ks], kf, sacc[mi][ni], 0, 0, 0);
            }

        const int kb0 = t * 128 + rr;
        float mx[2][4];
#pragma unroll
        for (int mi = 0; mi < 2; ++mi)
#pragma unroll
            for (int j = 0; j < 4; ++j) mx[mi][j] = -1e30f;
#pragma unroll
        for (int mi = 0; mi < 2; ++mi)
#pragma unroll
            for (int ni = 0; ni < 8; ++ni)
#pragma unroll
                for (int j = 0; j < 4; ++j) {
                    float sv = (kb0 + ni * 16 <= qbase + mi * 16 + j) ? sacc[mi][ni][j] : 0.f;
                    sacc[mi][ni][j] = sv;
                    mx[mi][j] = fmaxf(mx[mi][j], sv);
                }
#pragma unroll
        for (int mi = 0; mi < 2; ++mi)
#pragma unroll
            for (int j = 0; j < 4; ++j) {
                float v = mx[mi][j];
#pragma unroll
                for (int o = 1; o < 16; o <<= 1) v = fmaxf(v, __shfl_xor(v, o, 64));
                mx[mi][j] = v;
            }

        float rs[2][4];
#pragma unroll
        for (int mi = 0; mi < 2; ++mi)
#pragma unroll
            for (int j = 0; j < 4; ++j) {
                float mn = fmaxf(mrow[mi][j], mx[mi][j]);
                float sc = exp2f((mrow[mi][j] - mn) * L2E);
                mrow[mi][j] = mn;
                lrow[mi][j] *= sc;
                rs[mi][j] = 0.f;
#pragma unroll
                for (int ni = 0; ni < 4; ++ni) oacc[mi][ni][j] *= sc;
            }
#pragma unroll
        for (int mi = 0; mi < 2; ++mi)
#pragma unroll
            for (int ni = 0; ni < 8; ++ni)
#pragma unroll
                for (int j = 0; j < 4; ++j) {
                    float p = exp2f((sacc[mi][ni][j] - mrow[mi][j]) * L2E);
                    rs[mi][j] += p;
                    const int prow = mi * 16 + qq * 4 + j;
                    *(u16*)(Psb + prow * 256 +
                            (((rr + ni * 16) * 2) ^ ((prow & 7) << 4))) = f2b(p);
                }
#pragma unroll
        for (int mi = 0; mi < 2; ++mi)
#pragma unroll
            for (int j = 0; j < 4; ++j) {
                float v = rs[mi][j];
#pragma unroll
                for (int o = 1; o < 16; o <<= 1) v += __shfl_xor(v, o, 64);
                lrow[mi][j] += v;
            }

        WAITL0();

#pragma unroll
        for (int kk = 0; kk < 4; ++kk) {
            short8 pa[2], pv[4];
#pragma unroll
            for (int mi = 0; mi < 2; ++mi)
                pa[mi] = *(const short8*)(Psb + (mi * 16 + rr) * 256 +
                                          ((kk * 64 + qq * 16) ^ sxr));
#pragma unroll
            for (int ni = 0; ni < 4; ++ni)
                pv[ni] = *(const short8*)(Vsb + (rr + ni * 16) * 256 +
                                          ((kk * 64 + qq * 16) ^ sxr));
#pragma unroll
            for (int mi = 0; mi < 2; ++mi)
#pragma unroll
                for (int ni = 0; ni < 4; ++ni)
                    oacc[mi][ni] = __builtin_amdgcn_mfma_f32_16x16x32_bf16(
                        pa[mi], pv[ni], oacc[mi][ni], 0, 0, 0);
        }
        __syncthreads();
    }

    float inv[2][4];
#pragma unroll
    for (int mi = 0; mi < 2; ++mi)
#pragma unroll
        for (int j = 0; j < 4; ++j) inv[mi][j] = 1.0f / lrow[mi][j];
    u16* cb = ctx + ((size_t)bh << 16);
#pragma unroll
    for (int mi = 0; mi < 2; ++mi)
#pragma unroll
        for (int ni = 0; ni < 4; ++ni)
#pragma unroll
            for (int j = 0; j < 4; ++j) {
                const int srow = qt * 128 + w * 32 + mi * 16 + qq * 4 + j;
                cb[(size_t)srow * 64 + rr + ni * 16] = f2b(oacc[mi][ni][j] * inv[mi][j]);
            }
}

// ---------------------------------------------------------------------------
__global__ __launch_bounds__(256) void ln_bf16(
    const float* __restrict__ in, const float* __restrict__ gg,
    const float* __restrict__ bb, u16* __restrict__ outp,
    const int* __restrict__ iterp)
{
    const int row = blockIdx.x;
    const int t = threadIdx.x;
    const int lane = t & 63, w = t >> 6;
    const float* r = in + (size_t)row * DM;
    f32x4 x = *(const f32x4*)(r + t * 4);
    __shared__ float red[4];

    float s = x[0] + x[1] + x[2] + x[3];
#pragma unroll
    for (int o = 32; o; o >>= 1) s += __shfl_xor(s, o, 64);
    if (lane == 0) red[w] = s;
    __syncthreads();
    float mu = (red[0] + red[1] + red[2] + red[3]) * (1.0f / DM);
    __syncthreads();

    float d0 = x[0] - mu, d1 = x[1] - mu, d2 = x[2] - mu, d3 = x[3] - mu;
    float q = d0 * d0 + d1 * d1 + d2 * d2 + d3 * d3;
#pragma unroll
    for (int o = 32; o; o >>= 1) q += __shfl_xor(q, o, 64);
    if (lane == 0) red[w] = q;
    __syncthreads();
    float rs = rsqrtf((red[0] + red[1] + red[2] + red[3]) * (1.0f / DM) + 1e-6f);

    bool apply = !(iterp && iterp[0] == 0);
    f32x4 gv = *(const f32x4*)(gg + t * 4);
    f32x4 bv = *(const f32x4*)(bb + t * 4);
    us4 o;
    if (apply) {
        o[0] = f2b(d0 * rs * gv[0] + bv[0]);
        o[1] = f2b(d1 * rs * gv[1] + bv[1]);
        o[2] = f2b(d2 * rs * gv[2] + bv[2]);
        o[3] = f2b(d3 * rs * gv[3] + bv[3]);
    } else {
        o[0] = f2b(x[0]); o[1] = f2b(x[1]); o[2] = f2b(x[2]); o[3] = f2b(x[3]);
    }
    *(us4*)(outp + (size_t)row * DM + t * 4) = o;
}

__global__ void transW(const float* __restrict__ W, u16* __restrict__ WT, int Kd, int Nd)
{
    __shared__ float tile[32][33];
    int bx = blockIdx.x << 5, by = blockIdx.y << 5;
    int tx = threadIdx.x, ty = threadIdx.y;
#pragma unroll
    for (int i = 0; i < 32; i += 8)
        tile[ty + i][tx] = W[(size_t)(by + ty + i) * Nd + bx + tx];
    __syncthreads();
#pragma unroll
    for (int i = 0; i < 32; i += 8)
        WT[(size_t)(bx + ty + i) * Kd + by + tx] = f2b(tile[tx][ty + i]);
}

__global__ void transV(const u16* __restrict__ Vb, u16* __restrict__ Vt)
{
    __shared__ u16 tile[32][33];
    int s0 = blockIdx.x << 5, d0 = blockIdx.y << 5, bh = blockIdx.z;
    int b = bh >> 4, h = bh & 15;
    int tx = threadIdx.x, ty = threadIdx.y;
#pragma unroll
    for (int i = 0; i < 32; i += 8)
        tile[ty + i][tx] = Vb[(size_t)((b << 10) + s0 + ty + i) * DM + (h << 6) + d0 + tx];
    __syncthreads();
#pragma unroll
    for (int i = 0; i < 32; i += 8)
        Vt[((size_t)bh << 16) + (size_t)(d0 + ty + i) * SEQ + s0 + tx] = tile[tx][ty + i];
}

__global__ __launch_bounds__(256) void resid_add(
    const u16* __restrict__ ctx, const float* __restrict__ x, float* __restrict__ outp)
{
    size_t i = ((size_t)blockIdx.x * 256 + threadIdx.x) * 4;
    us4 c = *(const us4*)(ctx + i);
    f32x4 xv = *(const f32x4*)(x + i);
    f32x4 o;
#pragma unroll
    for (int j = 0; j < 4; j++) o[j] = xv[j] + b2f(c[j]);
    *(f32x4*)(outp + i) = o;
}

// ---------------------------------------------------------------------------
extern "C" void kernel_launch(void* const* d_in, const int* in_sizes, int n_in,
                              void* d_out, int out_size, void* d_ws, size_t ws_size,
                              hipStream_t stream)
{
    const int* iter = (const int*)d_in[0];
    const float* x = (const float*)d_in[1];
    const float* Wq = (const float*)d_in[3];
    const float* bq = (const float*)d_in[4];
    const float* Wk = (const float*)d_in[5];
    const float* bk = (const float*)d_in[6];
    const float* Wv = (const float*)d_in[7];
    const float* bv = (const float*)d_in[8];
    const float* W1 = (const float*)d_in[9];
    const float* b1 = (const float*)d_in[10];
    const float* W2 = (const float*)d_in[11];
    const float* b2 = (const float*)d_in[12];
    const float* lag = (const float*)d_in[13];
    const float* lab = (const float*)d_in[14];
    const float* lfg = (const float*)d_in[15];
    const float* lfb = (const float*)d_in[16];
    float* out = (float*)d_out;

    char* ws = (char*)d_ws;
    size_t off = 0;
    auto alloc = [&](size_t bytes) {
        char* p = ws + off;
        off += (bytes + 255) & ~(size_t)255;
        return p;
    };
    u16* NXb = (u16*)alloc((size_t)MROWS * DM * 2);
    u16* Qb  = (u16*)alloc((size_t)MROWS * DM * 2);
    u16* Kb  = (u16*)alloc((size_t)MROWS * DM * 2);
    u16* Vb  = (u16*)alloc((size_t)MROWS * DM * 2);
    u16* ctx = (u16*)alloc((size_t)MROWS * DM * 2);
    u16* h2  = (u16*)alloc((size_t)MROWS * DFF * 2);
    u16* WqT = (u16*)alloc((size_t)DM * DM * 2);
    u16* WkT = (u16*)alloc((size_t)DM * DM * 2);
    u16* WvT = (u16*)alloc((size_t)DM * DM * 2);
    u16* W1T = (u16*)alloc((size_t)DM * DFF * 2);
    u16* W2T = (u16*)alloc((size_t)DM * DFF * 2);
    u16* Vt = NXb;  // alias: NXb dead after projections
    u16* h1 = Qb;   // alias: Qb dead after attention

    dim3 tb(32, 8);
    transW<<<dim3(DM / 32, DM / 32), tb, 0, stream>>>(Wq, WqT, DM, DM);
    transW<<<dim3(DM / 32, DM / 32), tb, 0, stream>>>(Wk, WkT, DM, DM);
    transW<<<dim3(DM / 32, DM / 32), tb, 0, stream>>>(Wv, WvT, DM, DM);
    transW<<<dim3(DFF / 32, DM / 32), tb, 0, stream>>>(W1, W1T, DM, DFF);
    transW<<<dim3(DM / 32, DFF / 32), tb, 0, stream>>>(W2, W2T, DFF, DM);

    ln_bf16<<<MROWS, 256, 0, stream>>>(x, lag, lab, NXb, iter);

    // projections (gemm3, 3 blocks/CU): Q scaled by 1/sqrt(64)
    gemm3<0><<<dim3(DM / 128, MROWS / 128), 256, 0, stream>>>(
        NXb, DM, WqT, DM, Qb, DM, bq, 0.125f, DM);
    gemm3<0><<<dim3(DM / 128, MROWS / 128), 256, 0, stream>>>(
        NXb, DM, WkT, DM, Kb, DM, bk, 1.0f, DM);
    gemm3<0><<<dim3(DM / 128, MROWS / 128), 256, 0, stream>>>(
        NXb, DM, WvT, DM, Vb, DM, bv, 1.0f, DM);

    transV<<<dim3(SEQ / 32, DH / 32, B_N * NH), tb, 0, stream>>>(Vb, Vt);

    // fused flash attention
    flash_attn<<<dim3(SEQ / 128, B_N * NH), 256, 0, stream>>>(Qb, Kb, Vt, ctx);

    resid_add<<<(MROWS * DM) / 1024, 256, 0, stream>>>(ctx, x, out);

    // FFN: h1 = LN(out); h2 = gelu(h1@W1+b1) [gemm3]; out += h2@W2+b2 [gemm2 ctrl]
    ln_bf16<<<MROWS, 256, 0, stream>>>(out, lfg, lfb, h1, nullptr);
    gemm3<1><<<dim3(DFF / 128, MROWS / 128), 256, 0, stream>>>(
        h1, DM, W1T, DM, h2, DFF, b1, 1.0f, DM);
    gemm2<128, 2><<<dim3(DM / 256, MROWS / 128), 512, 0, stream>>>(
        h2, DFF, W2T, DFF, (void*)out, DM, b2, 1.0f, DFF);
}

// Round 9
// 435.168 us; speedup vs baseline: 1.8479x; 1.0714x over previous
//
#include <hip/hip_runtime.h>

// ---------------------------------------------------------------------------
// EncoderLayer: pre-LN attn (gated by iter!=0) + causal-mult-mask attention +
// residual + pre-LN FFN(GELU) + residual.  B=8 S=1024 D=1024 FF=4096 H=16 Dh=64
// R9: flash attention made L2/XCD-aware (bh-fastest grid: same-head q-tile
// blocks share an XCD's L2 for K/V) + fully-masked tiles (t>qt) replaced by a
// closed-form rank-1 update via per-tile V column sums (44% less tile work &
// K/V traffic). FFN2 moved to gemm3 (R8 A/B winner); gemm2 retired.
// ---------------------------------------------------------------------------

#define B_N 8
#define SEQ 1024
#define DM 1024
#define DFF 4096
#define NH 16
#define DH 64
#define MROWS (B_N * SEQ) // 8192

typedef __attribute__((ext_vector_type(4))) float f32x4;
typedef __attribute__((ext_vector_type(8))) short short8;
typedef __attribute__((ext_vector_type(4))) unsigned short us4;
typedef unsigned short u16;

__device__ __forceinline__ float b2f(u16 u) { return __uint_as_float(((unsigned)u) << 16); }
__device__ __forceinline__ u16 f2b(float f) {
    unsigned u = __float_as_uint(f);
    return (u16)((u + 0x7fffu + ((u >> 16) & 1u)) >> 16); // RNE
}
__device__ __forceinline__ float gelu_f(float x) {
    float t = tanhf(0.7978845608028654f * (x + 0.044715f * x * x * x));
    return 0.5f * x * (1.0f + t);
}
__device__ __forceinline__ void async_cp16(const void* g, void* l) {
    __builtin_amdgcn_global_load_lds(
        (const __attribute__((address_space(1))) unsigned int*)g,
        (__attribute__((address_space(3))) unsigned int*)l, 16, 0, 0);
}

#define WAITL0()                                                                \
    asm volatile("s_waitcnt lgkmcnt(0)" ::: "memory");                          \
    __builtin_amdgcn_sched_barrier(0)

// ---------------------------------------------------------------------------
// gemm3 (R8 winner): 256 thr = 4 waves (2x2), tile 128x128, BK=64, single-
// buffered 32KB LDS -> 3 blocks/CU (implicit inter-block overlap, m114).
// 0-conflict swizzle: read byte ^= ((row&7)<<4); stage source granule low3 ^=
// row&7.  EPI: 0 = bf16 out; 1 = bf16 GELU out; 2 = fp32 C += v
// ---------------------------------------------------------------------------
template <int EPI>
__global__ __launch_bounds__(256, 3) void gemm3(
    const u16* __restrict__ A, int lda,
    const u16* __restrict__ Bt, int ldb,
    void* __restrict__ C, int ldc,
    const float* __restrict__ bias, float scale, int K)
{
    __shared__ __align__(16) char lds[32768];

    const int tid = threadIdx.x;
    const int lane = tid & 63;
    const int w = tid >> 6;
    const int wm = w >> 1, wn = w & 1;
    const int rr = lane & 15, qq = lane >> 4;
    const int m0 = blockIdx.y * 128, n0 = blockIdx.x * 128;

    const int s = (rr & 7) << 4;
    const int swq = (qq * 16) ^ (s & 48);
    const int ksx[2] = { s & 64, 64 ^ (s & 64) };
    const int aoff = (wm * 64 + rr) * 128 + swq;
    const int boff = 16384 + (wn * 64 + rr) * 128 + swq;

    f32x4 acc[4][4];
#pragma unroll
    for (int i = 0; i < 4; i++)
#pragma unroll
        for (int j = 0; j < 4; j++)
#pragma unroll
            for (int e = 0; e < 4; e++) acc[i][j][e] = 0.f;

    const int NT = K >> 6;
    for (int t = 0; t < NT; ++t) {
#pragma unroll
        for (int i = 0; i < 4; ++i) {
            int g = tid + i * 256;
            int gs = (g & ~7) | ((g ^ (g >> 3)) & 7);
            async_cp16(A + (size_t)(m0 + (gs >> 3)) * lda + (t << 6) + ((gs & 7) << 3),
                       lds + g * 16);
        }
#pragma unroll
        for (int i = 0; i < 4; ++i) {
            int g = tid + i * 256;
            int gs = (g & ~7) | ((g ^ (g >> 3)) & 7);
            async_cp16(Bt + (size_t)(n0 + (gs >> 3)) * ldb + (t << 6) + ((gs & 7) << 3),
                       lds + 16384 + g * 16);
        }
        __syncthreads();

        short8 af[4][2], bfr[4][2];
#pragma unroll
        for (int mi = 0; mi < 4; ++mi)
#pragma unroll
            for (int ks = 0; ks < 2; ++ks)
                af[mi][ks] = *(const short8*)(lds + aoff + mi * 2048 + ksx[ks]);
#pragma unroll
        for (int ni = 0; ni < 4; ++ni)
#pragma unroll
            for (int ks = 0; ks < 2; ++ks)
                bfr[ni][ks] = *(const short8*)(lds + boff + ni * 2048 + ksx[ks]);
#pragma unroll
        for (int ks = 0; ks < 2; ++ks)
#pragma unroll
            for (int mi = 0; mi < 4; ++mi)
#pragma unroll
                for (int ni = 0; ni < 4; ++ni)
                    acc[mi][ni] = __builtin_amdgcn_mfma_f32_16x16x32_bf16(
                        af[mi][ks], bfr[ni][ks], acc[mi][ni], 0, 0, 0);
        __syncthreads();
    }

    const int ccol = n0 + wn * 64 + rr;
    const int crow = m0 + wm * 64 + qq * 4;
#pragma unroll
    for (int mi = 0; mi < 4; ++mi) {
#pragma unroll
        for (int ni = 0; ni < 4; ++ni) {
            const int colg = ccol + ni * 16;
            const float bv = bias ? bias[colg] : 0.f;
#pragma unroll
            for (int j = 0; j < 4; ++j) {
                const int rowg = crow + mi * 16 + j;
                float v = (acc[mi][ni][j] + bv) * scale;
                size_t idx = (size_t)rowg * ldc + colg;
                if (EPI == 1) v = gelu_f(v);
                if (EPI == 2) ((float*)C)[idx] += v;
                else ((u16*)C)[idx] = f2b(v);
            }
        }
    }
}

// ---------------------------------------------------------------------------
// Per-tile V column sums: Vcs[bh][t][d] = sum_{k in tile t} V[b, t*128+k, h, d]
// Used by flash_attn's fully-masked-tile rank-1 shortcut.
// ---------------------------------------------------------------------------
__global__ void vcolsum(const u16* __restrict__ Vb, float* __restrict__ Vcs)
{
    const int t = blockIdx.x, bh = blockIdx.y;
    const int b = bh >> 4, h = bh & 15;
    const int d = threadIdx.x;
    const u16* base = Vb + (size_t)(b * 1024 + t * 128) * DM + h * 64 + d;
    float s = 0.f;
#pragma unroll 8
    for (int k = 0; k < 128; ++k) s += b2f(base[(size_t)k * DM]);
    Vcs[((bh << 3) + t) * 64 + d] = s;
}

// ---------------------------------------------------------------------------
// Flash attention, multiplicative tril mask (masked scores = exactly 0 and
// INCLUDED in softmax: each masked key gets weight e^-M / Z).
// Grid (128 bh FASTEST, 8 qt): same-bh blocks land on one XCD (128%8==0) so
// K/V are L2-resident per XCD.  Only tiles t<=qt are materialized; the fully
// masked suffix (t>qt) is the closed-form rank-1 update
//   M=max(m,0); l=l*e^{m-M}+km*e^{-M}; O=O*e^{m-M}+e^{-M}*colsum(V_suffix).
// 4 waves x 32 q-rows, KV-tile 128, 64KB LDS, 2 blocks/CU.
// ---------------------------------------------------------------------------
__global__ __launch_bounds__(256, 2) void flash_attn(
    const u16* __restrict__ Qb, const u16* __restrict__ Kb,
    const u16* __restrict__ Vt, const float* __restrict__ Vcs,
    u16* __restrict__ ctx)
{
    constexpr float L2E = 1.44269504f;
    const int bh = blockIdx.x, qt = blockIdx.y;
    const int b = bh >> 4, h = bh & 15;
    const int tid = threadIdx.x, lane = tid & 63, w = tid >> 6;
    const int rr = lane & 15, qq = lane >> 4;

    __shared__ __align__(16) u16 smem[32768]; // 64KB
    char* Ksb = (char*)smem;                      // [128 keys][64 d]
    char* Vsb = (char*)(smem + 8192);             // [64 d][128 keys]
    char* Psb = (char*)(smem + 16384 + w * 4096); // per-wave [32][128]

    short8 qf[2][2];
    {
        const size_t qr = (size_t)(b * 1024 + qt * 128 + w * 32 + rr);
#pragma unroll
        for (int mi = 0; mi < 2; ++mi)
#pragma unroll
            for (int ks = 0; ks < 2; ++ks)
                qf[mi][ks] = *(const short8*)(Qb + (qr + mi * 16) * DM + h * 64 + ks * 32 + qq * 8);
    }

    f32x4 oacc[2][4];
    float mrow[2][4], lrow[2][4];
#pragma unroll
    for (int mi = 0; mi < 2; ++mi)
#pragma unroll
        for (int j = 0; j < 4; ++j) { mrow[mi][j] = -1e30f; lrow[mi][j] = 0.f; }
#pragma unroll
    for (int mi = 0; mi < 2; ++mi)
#pragma unroll
        for (int ni = 0; ni < 4; ++ni)
#pragma unroll
            for (int e = 0; e < 4; ++e) oacc[mi][ni][e] = 0.f;

    const u16* Kbase = Kb + (size_t)b * 1024 * DM + h * 64;
    const u16* Vbase = Vt + ((size_t)bh << 16);
    const int sxr = (rr & 7) << 4;
    const int qbase = qt * 128 + w * 32 + qq * 4;

    for (int t = 0; t <= qt; ++t) {
        // ---- stage K [128][64], V [64][128]; inverse-swizzled sources
#pragma unroll
        for (int i = 0; i < 4; ++i) {
            int g = tid + i * 256;
            int gs = (g & ~7) | ((g ^ (g >> 3)) & 7);
            async_cp16(Kbase + (size_t)(t * 128 + (gs >> 3)) * DM + ((gs & 7) << 3),
                       Ksb + g * 16);
        }
#pragma unroll
        for (int i = 0; i < 4; ++i) {
            int g = tid + i * 256;
            int gs = (g & ~7) | ((g ^ (g >> 4)) & 7);
            async_cp16(Vbase + (size_t)(gs >> 4) * SEQ + t * 128 + ((gs & 15) << 3),
                       Vsb + g * 16);
        }
        __syncthreads();

        // ---- S = Q K^T
        f32x4 sacc[2][8];
#pragma unroll
        for (int mi = 0; mi < 2; ++mi)
#pragma unroll
            for (int ni = 0; ni < 8; ++ni)
#pragma unroll
                for (int e = 0; e < 4; ++e) sacc[mi][ni][e] = 0.f;
#pragma unroll
        for (int ks = 0; ks < 2; ++ks)
#pragma unroll
            for (int ni = 0; ni < 8; ++ni) {
                short8 kf = *(const short8*)(Ksb + (rr + ni * 16) * 128 +
                                             ((ks * 64 + qq * 16) ^ sxr));
#pragma unroll
                for (int mi = 0; mi < 2; ++mi)
                    sacc[mi][ni] = __builtin_amdgcn_mfma_f32_16x16x32_bf16(
                        qf[mi][ks], kf, sacc[mi][ni], 0, 0, 0);
            }

        // ---- row max (diagonal tile: mask k>q to exactly 0, 0 included)
        float mx[2][4];
#pragma unroll
        for (int mi = 0; mi < 2; ++mi)
#pragma unroll
            for (int j = 0; j < 4; ++j) mx[mi][j] = -1e30f;
        if (t == qt) {
            const int kb0 = t * 128 + rr;
#pragma unroll
            for (int mi = 0; mi < 2; ++mi)
#pragma unroll
                for (int ni = 0; ni < 8; ++ni)
#pragma unroll
                    for (int j = 0; j < 4; ++j) {
                        float sv = (kb0 + ni * 16 <= qbase + mi * 16 + j) ? sacc[mi][ni][j] : 0.f;
                        sacc[mi][ni][j] = sv;
                        mx[mi][j] = fmaxf(mx[mi][j], sv);
                    }
        } else {
#pragma unroll
            for (int mi = 0; mi < 2; ++mi)
#pragma unroll
                for (int ni = 0; ni < 8; ++ni)
#pragma unroll
                    for (int j = 0; j < 4; ++j)
                        mx[mi][j] = fmaxf(mx[mi][j], sacc[mi][ni][j]);
        }
#pragma unroll
        for (int mi = 0; mi < 2; ++mi)
#pragma unroll
            for (int j = 0; j < 4; ++j) {
                float v = mx[mi][j];
#pragma unroll
                for (int o = 1; o < 16; o <<= 1) v = fmaxf(v, __shfl_xor(v, o, 64));
                mx[mi][j] = v;
            }

        // ---- online rescale + P = exp(S-m) -> bf16 LDS, row sums
        float rs[2][4];
#pragma unroll
        for (int mi = 0; mi < 2; ++mi)
#pragma unroll
            for (int j = 0; j < 4; ++j) {
                float mn = fmaxf(mrow[mi][j], mx[mi][j]);
                float sc = exp2f((mrow[mi][j] - mn) * L2E);
                mrow[mi][j] = mn;
                lrow[mi][j] *= sc;
                rs[mi][j] = 0.f;
#pragma unroll
                for (int ni = 0; ni < 4; ++ni) oacc[mi][ni][j] *= sc;
            }
#pragma unroll
        for (int mi = 0; mi < 2; ++mi)
#pragma unroll
            for (int ni = 0; ni < 8; ++ni)
#pragma unroll
                for (int j = 0; j < 4; ++j) {
                    float p = exp2f((sacc[mi][ni][j] - mrow[mi][j]) * L2E);
                    rs[mi][j] += p;
                    const int prow = mi * 16 + qq * 4 + j;
                    *(u16*)(Psb + prow * 256 +
                            (((rr + ni * 16) * 2) ^ ((prow & 7) << 4))) = f2b(p);
                }
#pragma unroll
        for (int mi = 0; mi < 2; ++mi)
#pragma unroll
            for (int j = 0; j < 4; ++j) {
                float v = rs[mi][j];
#pragma unroll
                for (int o = 1; o < 16; o <<= 1) v += __shfl_xor(v, o, 64);
                lrow[mi][j] += v;
            }

        WAITL0(); // own-wave P writes visible before P reads (rule #18 fence)

        // ---- O += P @ V
#pragma unroll
        for (int kk = 0; kk < 4; ++kk) {
            short8 pa[2], pv[4];
#pragma unroll
            for (int mi = 0; mi < 2; ++mi)
                pa[mi] = *(const short8*)(Psb + (mi * 16 + rr) * 256 +
                                          ((kk * 64 + qq * 16) ^ sxr));
#pragma unroll
            for (int ni = 0; ni < 4; ++ni)
                pv[ni] = *(const short8*)(Vsb + (rr + ni * 16) * 256 +
                                          ((kk * 64 + qq * 16) ^ sxr));
#pragma unroll
            for (int mi = 0; mi < 2; ++mi)
#pragma unroll
                for (int ni = 0; ni < 4; ++ni)
                    oacc[mi][ni] = __builtin_amdgcn_mfma_f32_16x16x32_bf16(
                        pa[mi], pv[ni], oacc[mi][ni], 0, 0, 0);
        }
        __syncthreads();
    }

    // ---- fully-masked suffix tiles (t>qt): rank-1 closed form
    if (qt < 7) {
        float vsuf[4] = { 0.f, 0.f, 0.f, 0.f };
        for (int tt = qt + 1; tt < 8; ++tt)
#pragma unroll
            for (int ni = 0; ni < 4; ++ni)
                vsuf[ni] += Vcs[((bh << 3) + tt) * 64 + rr + ni * 16];
        const float km = (float)((7 - qt) * 128);
#pragma unroll
        for (int mi = 0; mi < 2; ++mi)
#pragma unroll
            for (int j = 0; j < 4; ++j) {
                float m = mrow[mi][j];
                float mfin = fmaxf(m, 0.f);
                float sc = exp2f((m - mfin) * L2E);
                float w0 = exp2f(-mfin * L2E);
                lrow[mi][j] = lrow[mi][j] * sc + km * w0;
#pragma unroll
                for (int ni = 0; ni < 4; ++ni)
                    oacc[mi][ni][j] = oacc[mi][ni][j] * sc + w0 * vsuf[ni];
            }
    }

    // ---- epilogue: O/l -> ctx [bh][s][d]
    float inv[2][4];
#pragma unroll
    for (int mi = 0; mi < 2; ++mi)
#pragma unroll
        for (int j = 0; j < 4; ++j) inv[mi][j] = 1.0f / lrow[mi][j];
    u16* cb = ctx + ((size_t)bh << 16);
#pragma unroll
    for (int mi = 0; mi < 2; ++mi)
#pragma unroll
        for (int ni = 0; ni < 4; ++ni)
#pragma unroll
            for (int j = 0; j < 4; ++j) {
                const int srow = qt * 128 + w * 32 + mi * 16 + qq * 4 + j;
                cb[(size_t)srow * 64 + rr + ni * 16] = f2b(oacc[mi][ni][j] * inv[mi][j]);
            }
}

// ---------------------------------------------------------------------------
__global__ __launch_bounds__(256) void ln_bf16(
    const float* __restrict__ in, const float* __restrict__ gg,
    const float* __restrict__ bb, u16* __restrict__ outp,
    const int* __restrict__ iterp)
{
    const int row = blockIdx.x;
    const int t = threadIdx.x;
    const int lane = t & 63, w = t >> 6;
    const float* r = in + (size_t)row * DM;
    f32x4 x = *(const f32x4*)(r + t * 4);
    __shared__ float red[4];

    float s = x[0] + x[1] + x[2] + x[3];
#pragma unroll
    for (int o = 32; o; o >>= 1) s += __shfl_xor(s, o, 64);
    if (lane == 0) red[w] = s;
    __syncthreads();
    float mu = (red[0] + red[1] + red[2] + red[3]) * (1.0f / DM);
    __syncthreads();

    float d0 = x[0] - mu, d1 = x[1] - mu, d2 = x[2] - mu, d3 = x[3] - mu;
    float q = d0 * d0 + d1 * d1 + d2 * d2 + d3 * d3;
#pragma unroll
    for (int o = 32; o; o >>= 1) q += __shfl_xor(q, o, 64);
    if (lane == 0) red[w] = q;
    __syncthreads();
    float rs = rsqrtf((red[0] + red[1] + red[2] + red[3]) * (1.0f / DM) + 1e-6f);

    bool apply = !(iterp && iterp[0] == 0);
    f32x4 gv = *(const f32x4*)(gg + t * 4);
    f32x4 bv = *(const f32x4*)(bb + t * 4);
    us4 o;
    if (apply) {
        o[0] = f2b(d0 * rs * gv[0] + bv[0]);
        o[1] = f2b(d1 * rs * gv[1] + bv[1]);
        o[2] = f2b(d2 * rs * gv[2] + bv[2]);
        o[3] = f2b(d3 * rs * gv[3] + bv[3]);
    } else {
        o[0] = f2b(x[0]); o[1] = f2b(x[1]); o[2] = f2b(x[2]); o[3] = f2b(x[3]);
    }
    *(us4*)(outp + (size_t)row * DM + t * 4) = o;
}

__global__ void transW(const float* __restrict__ W, u16* __restrict__ WT, int Kd, int Nd)
{
    __shared__ float tile[32][33];
    int bx = blockIdx.x << 5, by = blockIdx.y << 5;
    int tx = threadIdx.x, ty = threadIdx.y;
#pragma unroll
    for (int i = 0; i < 32; i += 8)
        tile[ty + i][tx] = W[(size_t)(by + ty + i) * Nd + bx + tx];
    __syncthreads();
#pragma unroll
    for (int i = 0; i < 32; i += 8)
        WT[(size_t)(bx + ty + i) * Kd + by + tx] = f2b(tile[tx][ty + i]);
}

__global__ void transV(const u16* __restrict__ Vb, u16* __restrict__ Vt)
{
    __shared__ u16 tile[32][33];
    int s0 = blockIdx.x << 5, d0 = blockIdx.y << 5, bh = blockIdx.z;
    int b = bh >> 4, h = bh & 15;
    int tx = threadIdx.x, ty = threadIdx.y;
#pragma unroll
    for (int i = 0; i < 32; i += 8)
        tile[ty + i][tx] = Vb[(size_t)((b << 10) + s0 + ty + i) * DM + (h << 6) + d0 + tx];
    __syncthreads();
#pragma unroll
    for (int i = 0; i < 32; i += 8)
        Vt[((size_t)bh << 16) + (size_t)(d0 + ty + i) * SEQ + s0 + tx] = tile[tx][ty + i];
}

__global__ __launch_bounds__(256) void resid_add(
    const u16* __restrict__ ctx, const float* __restrict__ x, float* __restrict__ outp)
{
    size_t i = ((size_t)blockIdx.x * 256 + threadIdx.x) * 4;
    us4 c = *(const us4*)(ctx + i);
    f32x4 xv = *(const f32x4*)(x + i);
    f32x4 o;
#pragma unroll
    for (int j = 0; j < 4; j++) o[j] = xv[j] + b2f(c[j]);
    *(f32x4*)(outp + i) = o;
}

// ---------------------------------------------------------------------------
extern "C" void kernel_launch(void* const* d_in, const int* in_sizes, int n_in,
                              void* d_out, int out_size, void* d_ws, size_t ws_size,
                              hipStream_t stream)
{
    const int* iter = (const int*)d_in[0];
    const float* x = (const float*)d_in[1];
    const float* Wq = (const float*)d_in[3];
    const float* bq = (const float*)d_in[4];
    const float* Wk = (const float*)d_in[5];
    const float* bk = (const float*)d_in[6];
    const float* Wv = (const float*)d_in[7];
    const float* bv = (const float*)d_in[8];
    const float* W1 = (const float*)d_in[9];
    const float* b1 = (const float*)d_in[10];
    const float* W2 = (const float*)d_in[11];
    const float* b2 = (const float*)d_in[12];
    const float* lag = (const float*)d_in[13];
    const float* lab = (const float*)d_in[14];
    const float* lfg = (const float*)d_in[15];
    const float* lfb = (const float*)d_in[16];
    float* out = (float*)d_out;

    char* ws = (char*)d_ws;
    size_t off = 0;
    auto alloc = [&](size_t bytes) {
        char* p = ws + off;
        off += (bytes + 255) & ~(size_t)255;
        return p;
    };
    u16* NXb = (u16*)alloc((size_t)MROWS * DM * 2);
    u16* Qb  = (u16*)alloc((size_t)MROWS * DM * 2);
    u16* Kb  = (u16*)alloc((size_t)MROWS * DM * 2);
    u16* Vb  = (u16*)alloc((size_t)MROWS * DM * 2);
    u16* ctx = (u16*)alloc((size_t)MROWS * DM * 2);
    u16* h2  = (u16*)alloc((size_t)MROWS * DFF * 2);
    u16* WqT = (u16*)alloc((size_t)DM * DM * 2);
    u16* WkT = (u16*)alloc((size_t)DM * DM * 2);
    u16* WvT = (u16*)alloc((size_t)DM * DM * 2);
    u16* W1T = (u16*)alloc((size_t)DM * DFF * 2);
    u16* W2T = (u16*)alloc((size_t)DM * DFF * 2);
    float* Vcs = (float*)alloc((size_t)B_N * NH * 8 * 64 * 4); // 256KB
    u16* Vt = NXb;  // alias: NXb dead after projections
    u16* h1 = Qb;   // alias: Qb dead after attention

    dim3 tb(32, 8);
    transW<<<dim3(DM / 32, DM / 32), tb, 0, stream>>>(Wq, WqT, DM, DM);
    transW<<<dim3(DM / 32, DM / 32), tb, 0, stream>>>(Wk, WkT, DM, DM);
    transW<<<dim3(DM / 32, DM / 32), tb, 0, stream>>>(Wv, WvT, DM, DM);
    transW<<<dim3(DFF / 32, DM / 32), tb, 0, stream>>>(W1, W1T, DM, DFF);
    transW<<<dim3(DM / 32, DFF / 32), tb, 0, stream>>>(W2, W2T, DFF, DM);

    ln_bf16<<<MROWS, 256, 0, stream>>>(x, lag, lab, NXb, iter);

    // projections (gemm3): Q scaled by 1/sqrt(64)
    gemm3<0><<<dim3(DM / 128, MROWS / 128), 256, 0, stream>>>(
        NXb, DM, WqT, DM, Qb, DM, bq, 0.125f, DM);
    gemm3<0><<<dim3(DM / 128, MROWS / 128), 256, 0, stream>>>(
        NXb, DM, WkT, DM, Kb, DM, bk, 1.0f, DM);
    gemm3<0><<<dim3(DM / 128, MROWS / 128), 256, 0, stream>>>(
        NXb, DM, WvT, DM, Vb, DM, bv, 1.0f, DM);

    transV<<<dim3(SEQ / 32, DH / 32, B_N * NH), tb, 0, stream>>>(Vb, Vt);
    vcolsum<<<dim3(8, B_N * NH), 64, 0, stream>>>(Vb, Vcs);

    // fused flash attention (bh-fastest grid for XCD/L2 K/V locality)
    flash_attn<<<dim3(B_N * NH, SEQ / 128), 256, 0, stream>>>(Qb, Kb, Vt, Vcs, ctx);

    resid_add<<<(MROWS * DM) / 1024, 256, 0, stream>>>(ctx, x, out);

    // FFN: h1 = LN(out); h2 = gelu(h1@W1+b1); out += h2@W2+b2  (all gemm3)
    ln_bf16<<<MROWS, 256, 0, stream>>>(out, lfg, lfb, h1, nullptr);
    gemm3<1><<<dim3(DFF / 128, MROWS / 128), 256, 0, stream>>>(
        h1, DM, W1T, DM, h2, DFF, b1, 1.0f, DM);
    gemm3<2><<<dim3(DM / 128, MROWS / 128), 256, 0, stream>>>(
        h2, DFF, W2T, DFF, (void*)out, DM, b2, 1.0f, DFF);
}

// Round 10
// 389.358 us; speedup vs baseline: 2.0654x; 1.1177x over previous
//
#include <hip/hip_runtime.h>

// ---------------------------------------------------------------------------
// EncoderLayer: pre-LN attn (gated by iter!=0) + causal-mult-mask attention +
// residual + pre-LN FFN(GELU) + residual.  B=8 S=1024 D=1024 FF=4096 H=16 Dh=64
// R10: consolidation — (1) QKV projections fused into ONE gemm3 (N=3072,
// 1/8 scale folded into WqT/bq at transpose), (2) residual-add fused into
// flash epilogue (ctx linear == out linear, fp32 write), (3) hw-exp2 GELU.
// gemm3 inner loop unchanged (R8/R9 winner). Flash unchanged from R9.
// ---------------------------------------------------------------------------

#define B_N 8
#define SEQ 1024
#define DM 1024
#define DQKV 3072
#define DFF 4096
#define NH 16
#define DH 64
#define MROWS (B_N * SEQ) // 8192

typedef __attribute__((ext_vector_type(4))) float f32x4;
typedef __attribute__((ext_vector_type(8))) short short8;
typedef __attribute__((ext_vector_type(4))) unsigned short us4;
typedef unsigned short u16;

__device__ __forceinline__ float b2f(u16 u) { return __uint_as_float(((unsigned)u) << 16); }
__device__ __forceinline__ u16 f2b(float f) {
    unsigned u = __float_as_uint(f);
    return (u16)((u + 0x7fffu + ((u >> 16) & 1u)) >> 16); // RNE
}
// tanh-approx GELU via hw exp2/rcp: gelu(x) = x - x/(e^{2z}+1), z = c(x+0.044715x^3)
__device__ __forceinline__ float gelu_f(float x) {
    float x2 = x * x;
    float z2l = x * (2.3013935056f + 0.1029194997f * x2); // 2*log2(e)*c*(1, 0.044715)
    float t = exp2f(z2l);
    float r;
    asm("v_rcp_f32 %0, %1" : "=v"(r) : "v"(t + 1.0f));
    return x - x * r;
}
__device__ __forceinline__ void async_cp16(const void* g, void* l) {
    __builtin_amdgcn_global_load_lds(
        (const __attribute__((address_space(1))) unsigned int*)g,
        (__attribute__((address_space(3))) unsigned int*)l, 16, 0, 0);
}

#define WAITL0()                                                                \
    asm volatile("s_waitcnt lgkmcnt(0)" ::: "memory");                          \
    __builtin_amdgcn_sched_barrier(0)

// ---------------------------------------------------------------------------
// gemm3 (R8/R9 winner): 256 thr = 4 waves (2x2), tile 128x128, BK=64, single-
// buffered 32KB LDS -> high blocks/CU (implicit inter-block overlap, m114).
// 0-conflict swizzle: read byte ^= ((row&7)<<4); stage source granule low3 ^=
// row&7.  EPI: 0 = bf16 out; 1 = bf16 GELU out; 2 = fp32 C += v
// ---------------------------------------------------------------------------
template <int EPI>
__global__ __launch_bounds__(256, 3) void gemm3(
    const u16* __restrict__ A, int lda,
    const u16* __restrict__ Bt, int ldb,
    void* __restrict__ C, int ldc,
    const float* __restrict__ bias, float scale, int K)
{
    __shared__ __align__(16) char lds[32768];

    const int tid = threadIdx.x;
    const int lane = tid & 63;
    const int w = tid >> 6;
    const int wm = w >> 1, wn = w & 1;
    const int rr = lane & 15, qq = lane >> 4;
    const int m0 = blockIdx.y * 128, n0 = blockIdx.x * 128;

    const int s = (rr & 7) << 4;
    const int swq = (qq * 16) ^ (s & 48);
    const int ksx[2] = { s & 64, 64 ^ (s & 64) };
    const int aoff = (wm * 64 + rr) * 128 + swq;
    const int boff = 16384 + (wn * 64 + rr) * 128 + swq;

    f32x4 acc[4][4];
#pragma unroll
    for (int i = 0; i < 4; i++)
#pragma unroll
        for (int j = 0; j < 4; j++)
#pragma unroll
            for (int e = 0; e < 4; e++) acc[i][j][e] = 0.f;

    const int NT = K >> 6;
    for (int t = 0; t < NT; ++t) {
#pragma unroll
        for (int i = 0; i < 4; ++i) {
            int g = tid + i * 256;
            int gs = (g & ~7) | ((g ^ (g >> 3)) & 7);
            async_cp16(A + (size_t)(m0 + (gs >> 3)) * lda + (t << 6) + ((gs & 7) << 3),
                       lds + g * 16);
        }
#pragma unroll
        for (int i = 0; i < 4; ++i) {
            int g = tid + i * 256;
            int gs = (g & ~7) | ((g ^ (g >> 3)) & 7);
            async_cp16(Bt + (size_t)(n0 + (gs >> 3)) * ldb + (t << 6) + ((gs & 7) << 3),
                       lds + 16384 + g * 16);
        }
        __syncthreads();

        short8 af[4][2], bfr[4][2];
#pragma unroll
        for (int mi = 0; mi < 4; ++mi)
#pragma unroll
            for (int ks = 0; ks < 2; ++ks)
                af[mi][ks] = *(const short8*)(lds + aoff + mi * 2048 + ksx[ks]);
#pragma unroll
        for (int ni = 0; ni < 4; ++ni)
#pragma unroll
            for (int ks = 0; ks < 2; ++ks)
                bfr[ni][ks] = *(const short8*)(lds + boff + ni * 2048 + ksx[ks]);
#pragma unroll
        for (int ks = 0; ks < 2; ++ks)
#pragma unroll
            for (int mi = 0; mi < 4; ++mi)
#pragma unroll
                for (int ni = 0; ni < 4; ++ni)
                    acc[mi][ni] = __builtin_amdgcn_mfma_f32_16x16x32_bf16(
                        af[mi][ks], bfr[ni][ks], acc[mi][ni], 0, 0, 0);
        __syncthreads();
    }

    const int ccol = n0 + wn * 64 + rr;
    const int crow = m0 + wm * 64 + qq * 4;
#pragma unroll
    for (int mi = 0; mi < 4; ++mi) {
#pragma unroll
        for (int ni = 0; ni < 4; ++ni) {
            const int colg = ccol + ni * 16;
            const float bv = bias ? bias[colg] : 0.f;
#pragma unroll
            for (int j = 0; j < 4; ++j) {
                const int rowg = crow + mi * 16 + j;
                float v = (acc[mi][ni][j] + bv) * scale;
                size_t idx = (size_t)rowg * ldc + colg;
                if (EPI == 1) v = gelu_f(v);
                if (EPI == 2) ((float*)C)[idx] += v;
                else ((u16*)C)[idx] = f2b(v);
            }
        }
    }
}

// ---------------------------------------------------------------------------
// Per-tile V column sums from QKV (V = cols 2048+): Vcs[bh][t][d]
// ---------------------------------------------------------------------------
__global__ void vcolsum(const u16* __restrict__ QKV, float* __restrict__ Vcs)
{
    const int t = blockIdx.x, bh = blockIdx.y;
    const int b = bh >> 4, h = bh & 15;
    const int d = threadIdx.x;
    const u16* base = QKV + (size_t)(b * 1024 + t * 128) * DQKV + 2048 + h * 64 + d;
    float s = 0.f;
#pragma unroll 8
    for (int k = 0; k < 128; ++k) s += b2f(base[(size_t)k * DQKV]);
    Vcs[((bh << 3) + t) * 64 + d] = s;
}

// ---------------------------------------------------------------------------
// Flash attention (R9 structure), multiplicative tril mask, causal-skip +
// rank-1 suffix.  NEW: epilogue writes out = x + O/l directly (fp32) — the
// reference's context reshape is a flat linear identity, so ctx index == out
// index.  Q/K read from fused QKV (stride 3072).
// ---------------------------------------------------------------------------
__global__ __launch_bounds__(256, 2) void flash_attn(
    const u16* __restrict__ QKV, const u16* __restrict__ Vt,
    const float* __restrict__ Vcs, const float* __restrict__ x,
    float* __restrict__ outp)
{
    constexpr float L2E = 1.44269504f;
    const int bh = blockIdx.x, qt = blockIdx.y;
    const int b = bh >> 4, h = bh & 15;
    const int tid = threadIdx.x, lane = tid & 63, w = tid >> 6;
    const int rr = lane & 15, qq = lane >> 4;

    __shared__ __align__(16) u16 smem[32768]; // 64KB
    char* Ksb = (char*)smem;                      // [128 keys][64 d]
    char* Vsb = (char*)(smem + 8192);             // [64 d][128 keys]
    char* Psb = (char*)(smem + 16384 + w * 4096); // per-wave [32][128]

    short8 qf[2][2];
    {
        const size_t qr = (size_t)(b * 1024 + qt * 128 + w * 32 + rr);
#pragma unroll
        for (int mi = 0; mi < 2; ++mi)
#pragma unroll
            for (int ks = 0; ks < 2; ++ks)
                qf[mi][ks] = *(const short8*)(QKV + (qr + mi * 16) * DQKV + h * 64 + ks * 32 + qq * 8);
    }

    f32x4 oacc[2][4];
    float mrow[2][4], lrow[2][4];
#pragma unroll
    for (int mi = 0; mi < 2; ++mi)
#pragma unroll
        for (int j = 0; j < 4; ++j) { mrow[mi][j] = -1e30f; lrow[mi][j] = 0.f; }
#pragma unroll
    for (int mi = 0; mi < 2; ++mi)
#pragma unroll
        for (int ni = 0; ni < 4; ++ni)
#pragma unroll
            for (int e = 0; e < 4; ++e) oacc[mi][ni][e] = 0.f;

    const u16* Kbase = QKV + (size_t)b * 1024 * DQKV + 1024 + h * 64;
    const u16* Vbase = Vt + ((size_t)bh << 16);
    const int sxr = (rr & 7) << 4;
    const int qbase = qt * 128 + w * 32 + qq * 4;

    for (int t = 0; t <= qt; ++t) {
#pragma unroll
        for (int i = 0; i < 4; ++i) {
            int g = tid + i * 256;
            int gs = (g & ~7) | ((g ^ (g >> 3)) & 7);
            async_cp16(Kbase + (size_t)(t * 128 + (gs >> 3)) * DQKV + ((gs & 7) << 3),
                       Ksb + g * 16);
        }
#pragma unroll
        for (int i = 0; i < 4; ++i) {
            int g = tid + i * 256;
            int gs = (g & ~7) | ((g ^ (g >> 4)) & 7);
            async_cp16(Vbase + (size_t)(gs >> 4) * SEQ + t * 128 + ((gs & 15) << 3),
                       Vsb + g * 16);
        }
        __syncthreads();

        f32x4 sacc[2][8];
#pragma unroll
        for (int mi = 0; mi < 2; ++mi)
#pragma unroll
            for (int ni = 0; ni < 8; ++ni)
#pragma unroll
                for (int e = 0; e < 4; ++e) sacc[mi][ni][e] = 0.f;
#pragma unroll
        for (int ks = 0; ks < 2; ++ks)
#pragma unroll
            for (int ni = 0; ni < 8; ++ni) {
                short8 kf = *(const short8*)(Ksb + (rr + ni * 16) * 128 +
                                             ((ks * 64 + qq * 16) ^ sxr));
#pragma unroll
                for (int mi = 0; mi < 2; ++mi)
                    sacc[mi][ni] = __builtin_amdgcn_mfma_f32_16x16x32_bf16(
                        qf[mi][ks], kf, sacc[mi][ni], 0, 0, 0);
            }

        float mx[2][4];
#pragma unroll
        for (int mi = 0; mi < 2; ++mi)
#pragma unroll
            for (int j = 0; j < 4; ++j) mx[mi][j] = -1e30f;
        if (t == qt) {
            const int kb0 = t * 128 + rr;
#pragma unroll
            for (int mi = 0; mi < 2; ++mi)
#pragma unroll
                for (int ni = 0; ni < 8; ++ni)
#pragma unroll
                    for (int j = 0; j < 4; ++j) {
                        float sv = (kb0 + ni * 16 <= qbase + mi * 16 + j) ? sacc[mi][ni][j] : 0.f;
                        sacc[mi][ni][j] = sv;
                        mx[mi][j] = fmaxf(mx[mi][j], sv);
                    }
        } else {
#pragma unroll
            for (int mi = 0; mi < 2; ++mi)
#pragma unroll
                for (int ni = 0; ni < 8; ++ni)
#pragma unroll
                    for (int j = 0; j < 4; ++j)
                        mx[mi][j] = fmaxf(mx[mi][j], sacc[mi][ni][j]);
        }
#pragma unroll
        for (int mi = 0; mi < 2; ++mi)
#pragma unroll
            for (int j = 0; j < 4; ++j) {
                float v = mx[mi][j];
#pragma unroll
                for (int o = 1; o < 16; o <<= 1) v = fmaxf(v, __shfl_xor(v, o, 64));
                mx[mi][j] = v;
            }

        float rs[2][4];
#pragma unroll
        for (int mi = 0; mi < 2; ++mi)
#pragma unroll
            for (int j = 0; j < 4; ++j) {
                float mn = fmaxf(mrow[mi][j], mx[mi][j]);
                float sc = exp2f((mrow[mi][j] - mn) * L2E);
                mrow[mi][j] = mn;
                lrow[mi][j] *= sc;
                rs[mi][j] = 0.f;
#pragma unroll
                for (int ni = 0; ni < 4; ++ni) oacc[mi][ni][j] *= sc;
            }
#pragma unroll
        for (int mi = 0; mi < 2; ++mi)
#pragma unroll
            for (int ni = 0; ni < 8; ++ni)
#pragma unroll
                for (int j = 0; j < 4; ++j) {
                    float p = exp2f((sacc[mi][ni][j] - mrow[mi][j]) * L2E);
                    rs[mi][j] += p;
                    const int prow = mi * 16 + qq * 4 + j;
                    *(u16*)(Psb + prow * 256 +
                            (((rr + ni * 16) * 2) ^ ((prow & 7) << 4))) = f2b(p);
                }
#pragma unroll
        for (int mi = 0; mi < 2; ++mi)
#pragma unroll
            for (int j = 0; j < 4; ++j) {
                float v = rs[mi][j];
#pragma unroll
                for (int o = 1; o < 16; o <<= 1) v += __shfl_xor(v, o, 64);
                lrow[mi][j] += v;
            }

        WAITL0(); // own-wave P writes visible before P reads (rule #18 fence)

#pragma unroll
        for (int kk = 0; kk < 4; ++kk) {
            short8 pa[2], pv[4];
#pragma unroll
            for (int mi = 0; mi < 2; ++mi)
                pa[mi] = *(const short8*)(Psb + (mi * 16 + rr) * 256 +
                                          ((kk * 64 + qq * 16) ^ sxr));
#pragma unroll
            for (int ni = 0; ni < 4; ++ni)
                pv[ni] = *(const short8*)(Vsb + (rr + ni * 16) * 256 +
                                          ((kk * 64 + qq * 16) ^ sxr));
#pragma unroll
            for (int mi = 0; mi < 2; ++mi)
#pragma unroll
                for (int ni = 0; ni < 4; ++ni)
                    oacc[mi][ni] = __builtin_amdgcn_mfma_f32_16x16x32_bf16(
                        pa[mi], pv[ni], oacc[mi][ni], 0, 0, 0);
        }
        __syncthreads();
    }

    // fully-masked suffix tiles (t>qt): rank-1 closed form
    if (qt < 7) {
        float vsuf[4] = { 0.f, 0.f, 0.f, 0.f };
        for (int tt = qt + 1; tt < 8; ++tt)
#pragma unroll
            for (int ni = 0; ni < 4; ++ni)
                vsuf[ni] += Vcs[((bh << 3) + tt) * 64 + rr + ni * 16];
        const float km = (float)((7 - qt) * 128);
#pragma unroll
        for (int mi = 0; mi < 2; ++mi)
#pragma unroll
            for (int j = 0; j < 4; ++j) {
                float m = mrow[mi][j];
                float mfin = fmaxf(m, 0.f);
                float sc = exp2f((m - mfin) * L2E);
                float w0 = exp2f(-mfin * L2E);
                lrow[mi][j] = lrow[mi][j] * sc + km * w0;
#pragma unroll
                for (int ni = 0; ni < 4; ++ni)
                    oacc[mi][ni][j] = oacc[mi][ni][j] * sc + w0 * vsuf[ni];
            }
    }

    // epilogue: out = x + O/l  (fp32; flat-linear identity with ctx layout)
    float inv[2][4];
#pragma unroll
    for (int mi = 0; mi < 2; ++mi)
#pragma unroll
        for (int j = 0; j < 4; ++j) inv[mi][j] = 1.0f / lrow[mi][j];
    const float* xb = x + ((size_t)bh << 16);
    float* ob = outp + ((size_t)bh << 16);
#pragma unroll
    for (int mi = 0; mi < 2; ++mi)
#pragma unroll
        for (int ni = 0; ni < 4; ++ni)
#pragma unroll
            for (int j = 0; j < 4; ++j) {
                const size_t idx = (size_t)(qt * 128 + w * 32 + mi * 16 + qq * 4 + j) * 64
                                   + rr + ni * 16;
                ob[idx] = xb[idx] + oacc[mi][ni][j] * inv[mi][j];
            }
}

// ---------------------------------------------------------------------------
__global__ __launch_bounds__(256) void ln_bf16(
    const float* __restrict__ in, const float* __restrict__ gg,
    const float* __restrict__ bb, u16* __restrict__ outp,
    const int* __restrict__ iterp)
{
    const int row = blockIdx.x;
    const int t = threadIdx.x;
    const int lane = t & 63, w = t >> 6;
    const float* r = in + (size_t)row * DM;
    f32x4 x = *(const f32x4*)(r + t * 4);
    __shared__ float red[4];

    float s = x[0] + x[1] + x[2] + x[3];
#pragma unroll
    for (int o = 32; o; o >>= 1) s += __shfl_xor(s, o, 64);
    if (lane == 0) red[w] = s;
    __syncthreads();
    float mu = (red[0] + red[1] + red[2] + red[3]) * (1.0f / DM);
    __syncthreads();

    float d0 = x[0] - mu, d1 = x[1] - mu, d2 = x[2] - mu, d3 = x[3] - mu;
    float q = d0 * d0 + d1 * d1 + d2 * d2 + d3 * d3;
#pragma unroll
    for (int o = 32; o; o >>= 1) q += __shfl_xor(q, o, 64);
    if (lane == 0) red[w] = q;
    __syncthreads();
    float rs = rsqrtf((red[0] + red[1] + red[2] + red[3]) * (1.0f / DM) + 1e-6f);

    bool apply = !(iterp && iterp[0] == 0);
    f32x4 gv = *(const f32x4*)(gg + t * 4);
    f32x4 bv = *(const f32x4*)(bb + t * 4);
    us4 o;
    if (apply) {
        o[0] = f2b(d0 * rs * gv[0] + bv[0]);
        o[1] = f2b(d1 * rs * gv[1] + bv[1]);
        o[2] = f2b(d2 * rs * gv[2] + bv[2]);
        o[3] = f2b(d3 * rs * gv[3] + bv[3]);
    } else {
        o[0] = f2b(x[0]); o[1] = f2b(x[1]); o[2] = f2b(x[2]); o[3] = f2b(x[3]);
    }
    *(us4*)(outp + (size_t)row * DM + t * 4) = o;
}

// W [Kd][Nd] fp32 -> WT [Nd][Kd] bf16 with pre-scale (folds Q's 1/8 exactly)
__global__ void transW(const float* __restrict__ W, u16* __restrict__ WT,
                       int Kd, int Nd, float sc)
{
    __shared__ float tile[32][33];
    int bx = blockIdx.x << 5, by = blockIdx.y << 5;
    int tx = threadIdx.x, ty = threadIdx.y;
#pragma unroll
    for (int i = 0; i < 32; i += 8)
        tile[ty + i][tx] = W[(size_t)(by + ty + i) * Nd + bx + tx];
    __syncthreads();
#pragma unroll
    for (int i = 0; i < 32; i += 8)
        WT[(size_t)(bx + ty + i) * Kd + by + tx] = f2b(tile[tx][ty + i] * sc);
}

// V (QKV cols 2048+) -> Vt [B*H][Dh][S] bf16
__global__ void transV(const u16* __restrict__ QKV, u16* __restrict__ Vt)
{
    __shared__ u16 tile[32][33];
    int s0 = blockIdx.x << 5, d0 = blockIdx.y << 5, bh = blockIdx.z;
    int b = bh >> 4, h = bh & 15;
    int tx = threadIdx.x, ty = threadIdx.y;
#pragma unroll
    for (int i = 0; i < 32; i += 8)
        tile[ty + i][tx] = QKV[(size_t)((b << 10) + s0 + ty + i) * DQKV + 2048 + (h << 6) + d0 + tx];
    __syncthreads();
#pragma unroll
    for (int i = 0; i < 32; i += 8)
        Vt[((size_t)bh << 16) + (size_t)(d0 + ty + i) * SEQ + s0 + tx] = tile[tx][ty + i];
}

// bias pack: [bq*0.125 | bk | bv] -> bqkv[3072]
__global__ void pack_bias(const float* __restrict__ bq, const float* __restrict__ bk,
                          const float* __restrict__ bv, float* __restrict__ o)
{
    int i = blockIdx.x * 256 + threadIdx.x;
    float v = (i < 1024) ? bq[i] * 0.125f : ((i < 2048) ? bk[i - 1024] : bv[i - 2048]);
    o[i] = v;
}

// ---------------------------------------------------------------------------
extern "C" void kernel_launch(void* const* d_in, const int* in_sizes, int n_in,
                              void* d_out, int out_size, void* d_ws, size_t ws_size,
                              hipStream_t stream)
{
    const int* iter = (const int*)d_in[0];
    const float* x = (const float*)d_in[1];
    const float* Wq = (const float*)d_in[3];
    const float* bq = (const float*)d_in[4];
    const float* Wk = (const float*)d_in[5];
    const float* bk = (const float*)d_in[6];
    const float* Wv = (const float*)d_in[7];
    const float* bv = (const float*)d_in[8];
    const float* W1 = (const float*)d_in[9];
    const float* b1 = (const float*)d_in[10];
    const float* W2 = (const float*)d_in[11];
    const float* b2 = (const float*)d_in[12];
    const float* lag = (const float*)d_in[13];
    const float* lab = (const float*)d_in[14];
    const float* lfg = (const float*)d_in[15];
    const float* lfb = (const float*)d_in[16];
    float* out = (float*)d_out;

    char* ws = (char*)d_ws;
    size_t off = 0;
    auto alloc = [&](size_t bytes) {
        char* p = ws + off;
        off += (bytes + 255) & ~(size_t)255;
        return p;
    };
    u16* NXb  = (u16*)alloc((size_t)MROWS * DM * 2);        // 16.8MB; Vt alias later
    u16* QKV  = (u16*)alloc((size_t)MROWS * DQKV * 2);      // 50MB; h1 alias later
    u16* h2   = (u16*)alloc((size_t)MROWS * DFF * 2);       // 67MB
    u16* WqkvT = (u16*)alloc((size_t)DQKV * DM * 2);        // 6.3MB
    u16* W1T  = (u16*)alloc((size_t)DM * DFF * 2);
    u16* W2T  = (u16*)alloc((size_t)DM * DFF * 2);
    float* bqkv = (float*)alloc((size_t)DQKV * 4);
    float* Vcs = (float*)alloc((size_t)B_N * NH * 8 * 64 * 4);
    u16* Vt = NXb;  // alias: NXb dead after fused projection
    u16* h1 = QKV;  // alias: QKV dead after flash/transV

    dim3 tb(32, 8);
    // weight transposes into the fused [3072][1024] buffer (Q scaled by 1/8)
    transW<<<dim3(DM / 32, DM / 32), tb, 0, stream>>>(Wq, WqkvT, DM, DM, 0.125f);
    transW<<<dim3(DM / 32, DM / 32), tb, 0, stream>>>(Wk, WqkvT + (size_t)1024 * DM, DM, DM, 1.0f);
    transW<<<dim3(DM / 32, DM / 32), tb, 0, stream>>>(Wv, WqkvT + (size_t)2048 * DM, DM, DM, 1.0f);
    transW<<<dim3(DFF / 32, DM / 32), tb, 0, stream>>>(W1, W1T, DM, DFF, 1.0f);
    transW<<<dim3(DM / 32, DFF / 32), tb, 0, stream>>>(W2, W2T, DFF, DM, 1.0f);
    pack_bias<<<DQKV / 256, 256, 0, stream>>>(bq, bk, bv, bqkv);

    ln_bf16<<<MROWS, 256, 0, stream>>>(x, lag, lab, NXb, iter);

    // fused QKV projection: [8192][3072] = NXb @ [Wq|Wk|Wv] + bqkv
    gemm3<0><<<dim3(DQKV / 128, MROWS / 128), 256, 0, stream>>>(
        NXb, DM, WqkvT, DM, QKV, DQKV, bqkv, 1.0f, DM);

    transV<<<dim3(SEQ / 32, DH / 32, B_N * NH), tb, 0, stream>>>(QKV, Vt);
    vcolsum<<<dim3(8, B_N * NH), 64, 0, stream>>>(QKV, Vcs);

    // flash attention + fused residual (writes fp32 out directly)
    flash_attn<<<dim3(B_N * NH, SEQ / 128), 256, 0, stream>>>(QKV, Vt, Vcs, x, out);

    // FFN: h1 = LN(out); h2 = gelu(h1@W1+b1); out += h2@W2+b2
    ln_bf16<<<MROWS, 256, 0, stream>>>(out, lfg, lfb, h1, nullptr);
    gemm3<1><<<dim3(DFF / 128, MROWS / 128), 256, 0, stream>>>(
        h1, DM, W1T, DM, h2, DFF, b1, 1.0f, DM);
    gemm3<2><<<dim3(DM / 128, MROWS / 128), 256, 0, stream>>>(
        h2, DFF, W2T, DFF, (void*)out, DM, b2, 1.0f, DFF);
}

// Round 11
// 382.652 us; speedup vs baseline: 2.1016x; 1.0175x over previous
//
#include <hip/hip_runtime.h>

// ---------------------------------------------------------------------------
// EncoderLayer: pre-LN attn (gated by iter!=0) + causal-mult-mask attention +
// residual + pre-LN FFN(GELU) + residual.  B=8 S=1024 D=1024 FF=4096 H=16 Dh=64
// R11: single change vs R10 — chunked bijective XCD swizzle in gemm3 (T1).
// R10's FFN2 showed FETCH 282MB vs ~110MB algorithmic: with x-fastest ids each
// XCD touched EVERY A-panel. Chunked mapping gives each XCD a contiguous
// y-range -> per-K-step working set ~256KB, L2-resident per XCD.
// ---------------------------------------------------------------------------

#define B_N 8
#define SEQ 1024
#define DM 1024
#define DQKV 3072
#define DFF 4096
#define NH 16
#define DH 64
#define MROWS (B_N * SEQ) // 8192

typedef __attribute__((ext_vector_type(4))) float f32x4;
typedef __attribute__((ext_vector_type(8))) short short8;
typedef __attribute__((ext_vector_type(4))) unsigned short us4;
typedef unsigned short u16;

__device__ __forceinline__ float b2f(u16 u) { return __uint_as_float(((unsigned)u) << 16); }
__device__ __forceinline__ u16 f2b(float f) {
    unsigned u = __float_as_uint(f);
    return (u16)((u + 0x7fffu + ((u >> 16) & 1u)) >> 16); // RNE
}
// tanh-approx GELU via hw exp2/rcp: gelu(x) = x - x/(e^{2z}+1), z = c(x+0.044715x^3)
__device__ __forceinline__ float gelu_f(float x) {
    float x2 = x * x;
    float z2l = x * (2.3013935056f + 0.1029194997f * x2); // 2*log2(e)*c*(1, 0.044715)
    float t = exp2f(z2l);
    float r;
    asm("v_rcp_f32 %0, %1" : "=v"(r) : "v"(t + 1.0f));
    return x - x * r;
}
__device__ __forceinline__ void async_cp16(const void* g, void* l) {
    __builtin_amdgcn_global_load_lds(
        (const __attribute__((address_space(1))) unsigned int*)g,
        (__attribute__((address_space(3))) unsigned int*)l, 16, 0, 0);
}

#define WAITL0()                                                                \
    asm volatile("s_waitcnt lgkmcnt(0)" ::: "memory");                          \
    __builtin_amdgcn_sched_barrier(0)

// ---------------------------------------------------------------------------
// gemm3: 256 thr = 4 waves (2x2), tile 128x128, BK=64, single-buffered 32KB
// LDS -> ~3+ blocks/CU (implicit inter-block overlap, m114).  0-conflict
// swizzle: read byte ^= ((row&7)<<4); stage source granule low3 ^= row&7.
// R11: chunked XCD swizzle — XCD i (= flat%8 under round-robin dispatch) gets
// a CONTIGUOUS logical-id range -> same-y blocks share one XCD's L2.
// EPI: 0 = bf16 out; 1 = bf16 GELU out; 2 = fp32 C += v
// ---------------------------------------------------------------------------
template <int EPI>
__global__ __launch_bounds__(256, 3) void gemm3(
    const u16* __restrict__ A, int lda,
    const u16* __restrict__ Bt, int ldb,
    void* __restrict__ C, int ldc,
    const float* __restrict__ bias, float scale, int K)
{
    __shared__ __align__(16) char lds[32768];

    const int tid = threadIdx.x;
    const int lane = tid & 63;
    const int w = tid >> 6;
    const int wm = w >> 1, wn = w & 1;
    const int rr = lane & 15, qq = lane >> 4;

    // chunked bijective XCD swizzle (all grids here have nwg % 8 == 0)
    const int nwg = gridDim.x * gridDim.y;
    int flat = blockIdx.y * gridDim.x + blockIdx.x;
    flat = (flat & 7) * (nwg >> 3) + (flat >> 3);
    const int m0 = (flat / gridDim.x) * 128;
    const int n0 = (flat % gridDim.x) * 128;

    const int s = (rr & 7) << 4;
    const int swq = (qq * 16) ^ (s & 48);
    const int ksx[2] = { s & 64, 64 ^ (s & 64) };
    const int aoff = (wm * 64 + rr) * 128 + swq;
    const int boff = 16384 + (wn * 64 + rr) * 128 + swq;

    f32x4 acc[4][4];
#pragma unroll
    for (int i = 0; i < 4; i++)
#pragma unroll
        for (int j = 0; j < 4; j++)
#pragma unroll
            for (int e = 0; e < 4; e++) acc[i][j][e] = 0.f;

    const int NT = K >> 6;
    for (int t = 0; t < NT; ++t) {
#pragma unroll
        for (int i = 0; i < 4; ++i) {
            int g = tid + i * 256;
            int gs = (g & ~7) | ((g ^ (g >> 3)) & 7);
            async_cp16(A + (size_t)(m0 + (gs >> 3)) * lda + (t << 6) + ((gs & 7) << 3),
                       lds + g * 16);
        }
#pragma unroll
        for (int i = 0; i < 4; ++i) {
            int g = tid + i * 256;
            int gs = (g & ~7) | ((g ^ (g >> 3)) & 7);
            async_cp16(Bt + (size_t)(n0 + (gs >> 3)) * ldb + (t << 6) + ((gs & 7) << 3),
                       lds + 16384 + g * 16);
        }
        __syncthreads();

        short8 af[4][2], bfr[4][2];
#pragma unroll
        for (int mi = 0; mi < 4; ++mi)
#pragma unroll
            for (int ks = 0; ks < 2; ++ks)
                af[mi][ks] = *(const short8*)(lds + aoff + mi * 2048 + ksx[ks]);
#pragma unroll
        for (int ni = 0; ni < 4; ++ni)
#pragma unroll
            for (int ks = 0; ks < 2; ++ks)
                bfr[ni][ks] = *(const short8*)(lds + boff + ni * 2048 + ksx[ks]);
#pragma unroll
        for (int ks = 0; ks < 2; ++ks)
#pragma unroll
            for (int mi = 0; mi < 4; ++mi)
#pragma unroll
                for (int ni = 0; ni < 4; ++ni)
                    acc[mi][ni] = __builtin_amdgcn_mfma_f32_16x16x32_bf16(
                        af[mi][ks], bfr[ni][ks], acc[mi][ni], 0, 0, 0);
        __syncthreads();
    }

    const int ccol = n0 + wn * 64 + rr;
    const int crow = m0 + wm * 64 + qq * 4;
#pragma unroll
    for (int mi = 0; mi < 4; ++mi) {
#pragma unroll
        for (int ni = 0; ni < 4; ++ni) {
            const int colg = ccol + ni * 16;
            const float bv = bias ? bias[colg] : 0.f;
#pragma unroll
            for (int j = 0; j < 4; ++j) {
                const int rowg = crow + mi * 16 + j;
                float v = (acc[mi][ni][j] + bv) * scale;
                size_t idx = (size_t)rowg * ldc + colg;
                if (EPI == 1) v = gelu_f(v);
                if (EPI == 2) ((float*)C)[idx] += v;
                else ((u16*)C)[idx] = f2b(v);
            }
        }
    }
}

// ---------------------------------------------------------------------------
// Per-tile V column sums from QKV (V = cols 2048+): Vcs[bh][t][d]
// ---------------------------------------------------------------------------
__global__ void vcolsum(const u16* __restrict__ QKV, float* __restrict__ Vcs)
{
    const int t = blockIdx.x, bh = blockIdx.y;
    const int b = bh >> 4, h = bh & 15;
    const int d = threadIdx.x;
    const u16* base = QKV + (size_t)(b * 1024 + t * 128) * DQKV + 2048 + h * 64 + d;
    float s = 0.f;
#pragma unroll 8
    for (int k = 0; k < 128; ++k) s += b2f(base[(size_t)k * DQKV]);
    Vcs[((bh << 3) + t) * 64 + d] = s;
}

// ---------------------------------------------------------------------------
// Flash attention (R9/R10 structure): multiplicative tril mask, causal-skip +
// rank-1 suffix, residual fused into fp32 epilogue.  Q/K from fused QKV.
// ---------------------------------------------------------------------------
__global__ __launch_bounds__(256, 2) void flash_attn(
    const u16* __restrict__ QKV, const u16* __restrict__ Vt,
    const float* __restrict__ Vcs, const float* __restrict__ x,
    float* __restrict__ outp)
{
    constexpr float L2E = 1.44269504f;
    const int bh = blockIdx.x, qt = blockIdx.y;
    const int b = bh >> 4, h = bh & 15;
    const int tid = threadIdx.x, lane = tid & 63, w = tid >> 6;
    const int rr = lane & 15, qq = lane >> 4;

    __shared__ __align__(16) u16 smem[32768]; // 64KB
    char* Ksb = (char*)smem;                      // [128 keys][64 d]
    char* Vsb = (char*)(smem + 8192);             // [64 d][128 keys]
    char* Psb = (char*)(smem + 16384 + w * 4096); // per-wave [32][128]

    short8 qf[2][2];
    {
        const size_t qr = (size_t)(b * 1024 + qt * 128 + w * 32 + rr);
#pragma unroll
        for (int mi = 0; mi < 2; ++mi)
#pragma unroll
            for (int ks = 0; ks < 2; ++ks)
                qf[mi][ks] = *(const short8*)(QKV + (qr + mi * 16) * DQKV + h * 64 + ks * 32 + qq * 8);
    }

    f32x4 oacc[2][4];
    float mrow[2][4], lrow[2][4];
#pragma unroll
    for (int mi = 0; mi < 2; ++mi)
#pragma unroll
        for (int j = 0; j < 4; ++j) { mrow[mi][j] = -1e30f; lrow[mi][j] = 0.f; }
#pragma unroll
    for (int mi = 0; mi < 2; ++mi)
#pragma unroll
        for (int ni = 0; ni < 4; ++ni)
#pragma unroll
            for (int e = 0; e < 4; ++e) oacc[mi][ni][e] = 0.f;

    const u16* Kbase = QKV + (size_t)b * 1024 * DQKV + 1024 + h * 64;
    const u16* Vbase = Vt + ((size_t)bh << 16);
    const int sxr = (rr & 7) << 4;
    const int qbase = qt * 128 + w * 32 + qq * 4;

    for (int t = 0; t <= qt; ++t) {
#pragma unroll
        for (int i = 0; i < 4; ++i) {
            int g = tid + i * 256;
            int gs = (g & ~7) | ((g ^ (g >> 3)) & 7);
            async_cp16(Kbase + (size_t)(t * 128 + (gs >> 3)) * DQKV + ((gs & 7) << 3),
                       Ksb + g * 16);
        }
#pragma unroll
        for (int i = 0; i < 4; ++i) {
            int g = tid + i * 256;
            int gs = (g & ~7) | ((g ^ (g >> 4)) & 7);
            async_cp16(Vbase + (size_t)(gs >> 4) * SEQ + t * 128 + ((gs & 15) << 3),
                       Vsb + g * 16);
        }
        __syncthreads();

        f32x4 sacc[2][8];
#pragma unroll
        for (int mi = 0; mi < 2; ++mi)
#pragma unroll
            for (int ni = 0; ni < 8; ++ni)
#pragma unroll
                for (int e = 0; e < 4; ++e) sacc[mi][ni][e] = 0.f;
#pragma unroll
        for (int ks = 0; ks < 2; ++ks)
#pragma unroll
            for (int ni = 0; ni < 8; ++ni) {
                short8 kf = *(const short8*)(Ksb + (rr + ni * 16) * 128 +
                                             ((ks * 64 + qq * 16) ^ sxr));
#pragma unroll
                for (int mi = 0; mi < 2; ++mi)
                    sacc[mi][ni] = __builtin_amdgcn_mfma_f32_16x16x32_bf16(
                        qf[mi][ks], kf, sacc[mi][ni], 0, 0, 0);
            }

        float mx[2][4];
#pragma unroll
        for (int mi = 0; mi < 2; ++mi)
#pragma unroll
            for (int j = 0; j < 4; ++j) mx[mi][j] = -1e30f;
        if (t == qt) {
            const int kb0 = t * 128 + rr;
#pragma unroll
            for (int mi = 0; mi < 2; ++mi)
#pragma unroll
                for (int ni = 0; ni < 8; ++ni)
#pragma unroll
                    for (int j = 0; j < 4; ++j) {
                        float sv = (kb0 + ni * 16 <= qbase + mi * 16 + j) ? sacc[mi][ni][j] : 0.f;
                        sacc[mi][ni][j] = sv;
                        mx[mi][j] = fmaxf(mx[mi][j], sv);
                    }
        } else {
#pragma unroll
            for (int mi = 0; mi < 2; ++mi)
#pragma unroll
                for (int ni = 0; ni < 8; ++ni)
#pragma unroll
                    for (int j = 0; j < 4; ++j)
                        mx[mi][j] = fmaxf(mx[mi][j], sacc[mi][ni][j]);
        }
#pragma unroll
        for (int mi = 0; mi < 2; ++mi)
#pragma unroll
            for (int j = 0; j < 4; ++j) {
                float v = mx[mi][j];
#pragma unroll
                for (int o = 1; o < 16; o <<= 1) v = fmaxf(v, __shfl_xor(v, o, 64));
                mx[mi][j] = v;
            }

        float rs[2][4];
#pragma unroll
        for (int mi = 0; mi < 2; ++mi)
#pragma unroll
            for (int j = 0; j < 4; ++j) {
                float mn = fmaxf(mrow[mi][j], mx[mi][j]);
                float sc = exp2f((mrow[mi][j] - mn) * L2E);
                mrow[mi][j] = mn;
                lrow[mi][j] *= sc;
                rs[mi][j] = 0.f;
#pragma unroll
                for (int ni = 0; ni < 4; ++ni) oacc[mi][ni][j] *= sc;
            }
#pragma unroll
        for (int mi = 0; mi < 2; ++mi)
#pragma unroll
            for (int ni = 0; ni < 8; ++ni)
#pragma unroll
                for (int j = 0; j < 4; ++j) {
                    float p = exp2f((sacc[mi][ni][j] - mrow[mi][j]) * L2E);
                    rs[mi][j] += p;
                    const int prow = mi * 16 + qq * 4 + j;
                    *(u16*)(Psb + prow * 256 +
                            (((rr + ni * 16) * 2) ^ ((prow & 7) << 4))) = f2b(p);
                }
#pragma unroll
        for (int mi = 0; mi < 2; ++mi)
#pragma unroll
            for (int j = 0; j < 4; ++j) {
                float v = rs[mi][j];
#pragma unroll
                for (int o = 1; o < 16; o <<= 1) v += __shfl_xor(v, o, 64);
                lrow[mi][j] += v;
            }

        WAITL0(); // own-wave P writes visible before P reads (rule #18 fence)

#pragma unroll
        for (int kk = 0; kk < 4; ++kk) {
            short8 pa[2], pv[4];
#pragma unroll
            for (int mi = 0; mi < 2; ++mi)
                pa[mi] = *(const short8*)(Psb + (mi * 16 + rr) * 256 +
                                          ((kk * 64 + qq * 16) ^ sxr));
#pragma unroll
            for (int ni = 0; ni < 4; ++ni)
                pv[ni] = *(const short8*)(Vsb + (rr + ni * 16) * 256 +
                                          ((kk * 64 + qq * 16) ^ sxr));
#pragma unroll
            for (int mi = 0; mi < 2; ++mi)
#pragma unroll
                for (int ni = 0; ni < 4; ++ni)
                    oacc[mi][ni] = __builtin_amdgcn_mfma_f32_16x16x32_bf16(
                        pa[mi], pv[ni], oacc[mi][ni], 0, 0, 0);
        }
        __syncthreads();
    }

    // fully-masked suffix tiles (t>qt): rank-1 closed form
    if (qt < 7) {
        float vsuf[4] = { 0.f, 0.f, 0.f, 0.f };
        for (int tt = qt + 1; tt < 8; ++tt)
#pragma unroll
            for (int ni = 0; ni < 4; ++ni)
                vsuf[ni] += Vcs[((bh << 3) + tt) * 64 + rr + ni * 16];
        const float km = (float)((7 - qt) * 128);
#pragma unroll
        for (int mi = 0; mi < 2; ++mi)
#pragma unroll
            for (int j = 0; j < 4; ++j) {
                float m = mrow[mi][j];
                float mfin = fmaxf(m, 0.f);
                float sc = exp2f((m - mfin) * L2E);
                float w0 = exp2f(-mfin * L2E);
                lrow[mi][j] = lrow[mi][j] * sc + km * w0;
#pragma unroll
                for (int ni = 0; ni < 4; ++ni)
                    oacc[mi][ni][j] = oacc[mi][ni][j] * sc + w0 * vsuf[ni];
            }
    }

    // epilogue: out = x + O/l  (fp32; flat-linear identity with ctx layout)
    float inv[2][4];
#pragma unroll
    for (int mi = 0; mi < 2; ++mi)
#pragma unroll
        for (int j = 0; j < 4; ++j) inv[mi][j] = 1.0f / lrow[mi][j];
    const float* xb = x + ((size_t)bh << 16);
    float* ob = outp + ((size_t)bh << 16);
#pragma unroll
    for (int mi = 0; mi < 2; ++mi)
#pragma unroll
        for (int ni = 0; ni < 4; ++ni)
#pragma unroll
            for (int j = 0; j < 4; ++j) {
                const size_t idx = (size_t)(qt * 128 + w * 32 + mi * 16 + qq * 4 + j) * 64
                                   + rr + ni * 16;
                ob[idx] = xb[idx] + oacc[mi][ni][j] * inv[mi][j];
            }
}

// ---------------------------------------------------------------------------
__global__ __launch_bounds__(256) void ln_bf16(
    const float* __restrict__ in, const float* __restrict__ gg,
    const float* __restrict__ bb, u16* __restrict__ outp,
    const int* __restrict__ iterp)
{
    const int row = blockIdx.x;
    const int t = threadIdx.x;
    const int lane = t & 63, w = t >> 6;
    const float* r = in + (size_t)row * DM;
    f32x4 x = *(const f32x4*)(r + t * 4);
    __shared__ float red[4];

    float s = x[0] + x[1] + x[2] + x[3];
#pragma unroll
    for (int o = 32; o; o >>= 1) s += __shfl_xor(s, o, 64);
    if (lane == 0) red[w] = s;
    __syncthreads();
    float mu = (red[0] + red[1] + red[2] + red[3]) * (1.0f / DM);
    __syncthreads();

    float d0 = x[0] - mu, d1 = x[1] - mu, d2 = x[2] - mu, d3 = x[3] - mu;
    float q = d0 * d0 + d1 * d1 + d2 * d2 + d3 * d3;
#pragma unroll
    for (int o = 32; o; o >>= 1) q += __shfl_xor(q, o, 64);
    if (lane == 0) red[w] = q;
    __syncthreads();
    float rs = rsqrtf((red[0] + red[1] + red[2] + red[3]) * (1.0f / DM) + 1e-6f);

    bool apply = !(iterp && iterp[0] == 0);
    f32x4 gv = *(const f32x4*)(gg + t * 4);
    f32x4 bv = *(const f32x4*)(bb + t * 4);
    us4 o;
    if (apply) {
        o[0] = f2b(d0 * rs * gv[0] + bv[0]);
        o[1] = f2b(d1 * rs * gv[1] + bv[1]);
        o[2] = f2b(d2 * rs * gv[2] + bv[2]);
        o[3] = f2b(d3 * rs * gv[3] + bv[3]);
    } else {
        o[0] = f2b(x[0]); o[1] = f2b(x[1]); o[2] = f2b(x[2]); o[3] = f2b(x[3]);
    }
    *(us4*)(outp + (size_t)row * DM + t * 4) = o;
}

// W [Kd][Nd] fp32 -> WT [Nd][Kd] bf16 with pre-scale (folds Q's 1/8 exactly)
__global__ void transW(const float* __restrict__ W, u16* __restrict__ WT,
                       int Kd, int Nd, float sc)
{
    __shared__ float tile[32][33];
    int bx = blockIdx.x << 5, by = blockIdx.y << 5;
    int tx = threadIdx.x, ty = threadIdx.y;
#pragma unroll
    for (int i = 0; i < 32; i += 8)
        tile[ty + i][tx] = W[(size_t)(by + ty + i) * Nd + bx + tx];
    __syncthreads();
#pragma unroll
    for (int i = 0; i < 32; i += 8)
        WT[(size_t)(bx + ty + i) * Kd + by + tx] = f2b(tile[tx][ty + i] * sc);
}

// V (QKV cols 2048+) -> Vt [B*H][Dh][S] bf16
__global__ void transV(const u16* __restrict__ QKV, u16* __restrict__ Vt)
{
    __shared__ u16 tile[32][33];
    int s0 = blockIdx.x << 5, d0 = blockIdx.y << 5, bh = blockIdx.z;
    int b = bh >> 4, h = bh & 15;
    int tx = threadIdx.x, ty = threadIdx.y;
#pragma unroll
    for (int i = 0; i < 32; i += 8)
        tile[ty + i][tx] = QKV[(size_t)((b << 10) + s0 + ty + i) * DQKV + 2048 + (h << 6) + d0 + tx];
    __syncthreads();
#pragma unroll
    for (int i = 0; i < 32; i += 8)
        Vt[((size_t)bh << 16) + (size_t)(d0 + ty + i) * SEQ + s0 + tx] = tile[tx][ty + i];
}

// bias pack: [bq*0.125 | bk | bv] -> bqkv[3072]
__global__ void pack_bias(const float* __restrict__ bq, const float* __restrict__ bk,
                          const float* __restrict__ bv, float* __restrict__ o)
{
    int i = blockIdx.x * 256 + threadIdx.x;
    float v = (i < 1024) ? bq[i] * 0.125f : ((i < 2048) ? bk[i - 1024] : bv[i - 2048]);
    o[i] = v;
}

// ---------------------------------------------------------------------------
extern "C" void kernel_launch(void* const* d_in, const int* in_sizes, int n_in,
                              void* d_out, int out_size, void* d_ws, size_t ws_size,
                              hipStream_t stream)
{
    const int* iter = (const int*)d_in[0];
    const float* x = (const float*)d_in[1];
    const float* Wq = (const float*)d_in[3];
    const float* bq = (const float*)d_in[4];
    const float* Wk = (const float*)d_in[5];
    const float* bk = (const float*)d_in[6];
    const float* Wv = (const float*)d_in[7];
    const float* bv = (const float*)d_in[8];
    const float* W1 = (const float*)d_in[9];
    const float* b1 = (const float*)d_in[10];
    const float* W2 = (const float*)d_in[11];
    const float* b2 = (const float*)d_in[12];
    const float* lag = (const float*)d_in[13];
    const float* lab = (const float*)d_in[14];
    const float* lfg = (const float*)d_in[15];
    const float* lfb = (const float*)d_in[16];
    float* out = (float*)d_out;

    char* ws = (char*)d_ws;
    size_t off = 0;
    auto alloc = [&](size_t bytes) {
        char* p = ws + off;
        off += (bytes + 255) & ~(size_t)255;
        return p;
    };
    u16* NXb  = (u16*)alloc((size_t)MROWS * DM * 2);        // Vt alias later
    u16* QKV  = (u16*)alloc((size_t)MROWS * DQKV * 2);      // h1 alias later
    u16* h2   = (u16*)alloc((size_t)MROWS * DFF * 2);
    u16* WqkvT = (u16*)alloc((size_t)DQKV * DM * 2);
    u16* W1T  = (u16*)alloc((size_t)DM * DFF * 2);
    u16* W2T  = (u16*)alloc((size_t)DM * DFF * 2);
    float* bqkv = (float*)alloc((size_t)DQKV * 4);
    float* Vcs = (float*)alloc((size_t)B_N * NH * 8 * 64 * 4);
    u16* Vt = NXb;  // alias: NXb dead after fused projection
    u16* h1 = QKV;  // alias: QKV dead after flash/transV

    dim3 tb(32, 8);
    transW<<<dim3(DM / 32, DM / 32), tb, 0, stream>>>(Wq, WqkvT, DM, DM, 0.125f);
    transW<<<dim3(DM / 32, DM / 32), tb, 0, stream>>>(Wk, WqkvT + (size_t)1024 * DM, DM, DM, 1.0f);
    transW<<<dim3(DM / 32, DM / 32), tb, 0, stream>>>(Wv, WqkvT + (size_t)2048 * DM, DM, DM, 1.0f);
    transW<<<dim3(DFF / 32, DM / 32), tb, 0, stream>>>(W1, W1T, DM, DFF, 1.0f);
    transW<<<dim3(DM / 32, DFF / 32), tb, 0, stream>>>(W2, W2T, DFF, DM, 1.0f);
    pack_bias<<<DQKV / 256, 256, 0, stream>>>(bq, bk, bv, bqkv);

    ln_bf16<<<MROWS, 256, 0, stream>>>(x, lag, lab, NXb, iter);

    // fused QKV projection
    gemm3<0><<<dim3(DQKV / 128, MROWS / 128), 256, 0, stream>>>(
        NXb, DM, WqkvT, DM, QKV, DQKV, bqkv, 1.0f, DM);

    transV<<<dim3(SEQ / 32, DH / 32, B_N * NH), tb, 0, stream>>>(QKV, Vt);
    vcolsum<<<dim3(8, B_N * NH), 64, 0, stream>>>(QKV, Vcs);

    // flash attention + fused residual
    flash_attn<<<dim3(B_N * NH, SEQ / 128), 256, 0, stream>>>(QKV, Vt, Vcs, x, out);

    // FFN
    ln_bf16<<<MROWS, 256, 0, stream>>>(out, lfg, lfb, h1, nullptr);
    gemm3<1><<<dim3(DFF / 128, MROWS / 128), 256, 0, stream>>>(
        h1, DM, W1T, DM, h2, DFF, b1, 1.0f, DM);
    gemm3<2><<<dim3(DM / 128, MROWS / 128), 256, 0, stream>>>(
        h2, DFF, W2T, DFF, (void*)out, DM, b2, 1.0f, DFF);
}